// Round 6
// baseline (125.002 us; speedup 1.0000x reference)
//
#include <hip/hip_runtime.h>
#include <hip/hip_bf16.h>
#include <math.h>

typedef __attribute__((ext_vector_type(8))) short short8;
typedef __attribute__((ext_vector_type(4))) float f32x4;
typedef unsigned int u32;
typedef unsigned short u16;

#define DDIM 512
#define KCL 64
#define NPOS 4096
#define NSPL 8
#define EPSF 1e-12f

__device__ __forceinline__ u16 f2bf(float x) {
    __hip_bfloat16 h = __float2bfloat16(x);
    return __builtin_bit_cast(u16, h);
}
__device__ __forceinline__ float bf2f(u16 u) {
    unsigned i = ((unsigned)u) << 16;
    return __builtin_bit_cast(float, i);
}
// pack x as bf16(hi) | bf16(residual lo) << 16
__device__ __forceinline__ u32 packf(float x) {
    u16 h = f2bf(x);
    u16 l = f2bf(x - bf2f(h));
    return (u32)h | ((u32)l << 16);
}
// 8 packed u32 (as 4 uint2) -> hi/lo bf16 short8
__device__ __forceinline__ void unpk2(uint2 a0, uint2 a1, uint2 a2, uint2 a3,
                                      short8& hi, short8& lo) {
    uint4 H, L;
    H.x = (a0.x & 0xffffu) | (a0.y << 16);
    L.x = (a0.x >> 16)     | (a0.y & 0xffff0000u);
    H.y = (a1.x & 0xffffu) | (a1.y << 16);
    L.y = (a1.x >> 16)     | (a1.y & 0xffff0000u);
    H.z = (a2.x & 0xffffu) | (a2.y << 16);
    L.z = (a2.x >> 16)     | (a2.y & 0xffff0000u);
    H.w = (a3.x & 0xffffu) | (a3.y << 16);
    L.w = (a3.x >> 16)     | (a3.y & 0xffff0000u);
    hi = __builtin_bit_cast(short8, H);
    lo = __builtin_bit_cast(short8, L);
}
__device__ __forceinline__ void unpk4(uint4 p0, uint4 p1, short8& hi, short8& lo) {
    unpk2(make_uint2(p0.x, p0.y), make_uint2(p0.z, p0.w),
          make_uint2(p1.x, p1.y), make_uint2(p1.z, p1.w), hi, lo);
}

// ---------------------------------------------------------------------------
// W [64][512] fp32 -> packed u32 (bf16 hi | lo<<16), same layout
__global__ __launch_bounds__(256) void k_wsplit(const float* __restrict__ W,
                                                u32* __restrict__ Wp) {
    int i = blockIdx.x * 256 + threadIdx.x;
    Wp[i] = packf(W[i]);
}

// ---------------------------------------------------------------------------
// scores = softmax_k(W @ desc + b) -> P packed u32 [B][K][N], pssum partials.
// grid (32 nblk, B), 256 thr = 4 waves x (64k x 32n). Split-bf16: hh+lh+hl.
// W-frags read directly from global (L2-resident); desc staged transposed+packed
// DT[n][d] u32 pitch 66 (scalar b32 writes; b64 frag reads, 2-way banks).
__global__ __launch_bounds__(256) void k_scores(const float* __restrict__ desc,
        const u32* __restrict__ Wp, const float* __restrict__ bias,
        u32* __restrict__ P, float* __restrict__ pssum) {
    const int nblk = blockIdx.x, b = blockIdx.y;
    const int t = threadIdx.x;
    const int w = t >> 6, lane = t & 63, c = lane & 15, g = lane >> 4;

    __shared__ u32 DT[128][66];   // [n][d] packed

    f32x4 acc[4][2];
#pragma unroll
    for (int mf = 0; mf < 4; ++mf)
#pragma unroll
        for (int nf = 0; nf < 2; ++nf) acc[mf][nf] = (f32x4){0.f, 0.f, 0.f, 0.f};

    f32x4 bv[4];
#pragma unroll
    for (int mf = 0; mf < 4; ++mf) bv[mf] = *(const f32x4*)&bias[mf * 16 + g * 4];

    const int rl = t >> 2, q = t & 3;

    for (int dt = 0; dt < 8; ++dt) {
        const int d0 = dt * 64;
        // issue W-frag global loads early (hide L2 latency under staging)
        uint4 wp0[2][4], wp1[2][4];
#pragma unroll
        for (int ks = 0; ks < 2; ++ks) {
            const int kk = ks * 32 + g * 8;
#pragma unroll
            for (int mf = 0; mf < 4; ++mf) {
                const u32* wr = Wp + (size_t)(mf * 16 + c) * DDIM + d0 + kk;
                wp0[ks][mf] = *(const uint4*)&wr[0];
                wp1[ks][mf] = *(const uint4*)&wr[4];
            }
        }
        // stage desc tile [64d][128n] -> DT[n][d] packed (transpose via scalar b32)
        {
            const float* dsrc = desc + ((size_t)b * DDIM + d0 + rl) * NPOS + nblk * 128;
#pragma unroll
            for (int u = 0; u < 8; ++u) {
                const int n = u * 16 + q * 4;
                float4 dv = *(const float4*)&dsrc[n];
                DT[n + 0][rl] = packf(dv.x);
                DT[n + 1][rl] = packf(dv.y);
                DT[n + 2][rl] = packf(dv.z);
                DT[n + 3][rl] = packf(dv.w);
            }
        }
        __syncthreads();
#pragma unroll
        for (int ks = 0; ks < 2; ++ks) {
            const int kk = ks * 32 + g * 8;
            short8 ah[4], al[4];
#pragma unroll
            for (int mf = 0; mf < 4; ++mf) unpk4(wp0[ks][mf], wp1[ks][mf], ah[mf], al[mf]);
#pragma unroll
            for (int nf = 0; nf < 2; ++nf) {
                const int nc = w * 32 + nf * 16 + c;
                const u32* dr = &DT[nc][kk];
                uint2 a0 = *(const uint2*)&dr[0];
                uint2 a1 = *(const uint2*)&dr[2];
                uint2 a2 = *(const uint2*)&dr[4];
                uint2 a3 = *(const uint2*)&dr[6];
                short8 bh, bl;
                unpk2(a0, a1, a2, a3, bh, bl);
#pragma unroll
                for (int mf = 0; mf < 4; ++mf) {
                    acc[mf][nf] = __builtin_amdgcn_mfma_f32_16x16x32_bf16(ah[mf], bh, acc[mf][nf], 0, 0, 0);
                    acc[mf][nf] = __builtin_amdgcn_mfma_f32_16x16x32_bf16(al[mf], bh, acc[mf][nf], 0, 0, 0);
                    acc[mf][nf] = __builtin_amdgcn_mfma_f32_16x16x32_bf16(ah[mf], bl, acc[mf][nf], 0, 0, 0);
                }
            }
        }
        __syncthreads();
    }

    // epilogue: +bias, softmax over 64 k, pack+store P, ssum partials
#pragma unroll
    for (int mf = 0; mf < 4; ++mf)
#pragma unroll
        for (int nf = 0; nf < 2; ++nf) acc[mf][nf] = acc[mf][nf] + bv[mf];

    float ps[4][4];
#pragma unroll
    for (int mf = 0; mf < 4; ++mf)
#pragma unroll
        for (int r = 0; r < 4; ++r) ps[mf][r] = 0.f;

#pragma unroll
    for (int nf = 0; nf < 2; ++nf) {
        float m = acc[0][nf][0];
#pragma unroll
        for (int mf = 0; mf < 4; ++mf)
#pragma unroll
            for (int r = 0; r < 4; ++r) m = fmaxf(m, acc[mf][nf][r]);
        m = fmaxf(m, __shfl_xor(m, 16));
        m = fmaxf(m, __shfl_xor(m, 32));
        float s = 0.f;
#pragma unroll
        for (int mf = 0; mf < 4; ++mf)
#pragma unroll
            for (int r = 0; r < 4; ++r) {
                float p = __expf(acc[mf][nf][r] - m);
                acc[mf][nf][r] = p;
                s += p;
            }
        s += __shfl_xor(s, 16);
        s += __shfl_xor(s, 32);
        const float inv = 1.0f / s;
        const int n = nblk * 128 + w * 32 + nf * 16 + c;
#pragma unroll
        for (int mf = 0; mf < 4; ++mf) {
#pragma unroll
            for (int r = 0; r < 4; ++r) {
                float p = acc[mf][nf][r] * inv;
                ps[mf][r] += p;
                const int k = mf * 16 + g * 4 + r;
                P[((size_t)b * KCL + k) * NPOS + n] = packf(p);
            }
        }
    }
#pragma unroll
    for (int mf = 0; mf < 4; ++mf)
#pragma unroll
        for (int r = 0; r < 4; ++r) {
            float v = ps[mf][r];
            v += __shfl_xor(v, 1);
            v += __shfl_xor(v, 2);
            v += __shfl_xor(v, 4);
            v += __shfl_xor(v, 8);
            ps[mf][r] = v;
        }
    if (c == 0) {
#pragma unroll
        for (int mf = 0; mf < 4; ++mf) {
            float4 o = make_float4(ps[mf][0], ps[mf][1], ps[mf][2], ps[mf][3]);
            *(float4*)&pssum[((size_t)b * 128 + nblk * 4 + w) * KCL + mf * 16 + g * 4] = o;
        }
    }
}

// ---------------------------------------------------------------------------
// part[ns][b][k][d] = sum_{n in slice} desc[b][d][n] * P[b][n][k]
// grid (4 dblk, 8 ns, B), 256 thr; tile [128d][64k]. Packed u32 tiles, pitch 66,
// b64 fragment reads (2-way banks).
__global__ __launch_bounds__(256) void k_agg(const float* __restrict__ desc,
        const u32* __restrict__ P, float* __restrict__ part, int B) {
    const int dblk = blockIdx.x, ns = blockIdx.y, b = blockIdx.z;
    const int t = threadIdx.x;
    const int w = t >> 6, lane = t & 63, c = lane & 15, g = lane >> 4;
    const int wm = w & 1, wk = w >> 1;

    __shared__ u32 Apk[128][66];   // desc packed [d][n]
    __shared__ u32 Pt[64][66];     // P packed [k][n]

    f32x4 acc[4][2];
#pragma unroll
    for (int mf = 0; mf < 4; ++mf)
#pragma unroll
        for (int nf = 0; nf < 2; ++nf) acc[mf][nf] = (f32x4){0.f, 0.f, 0.f, 0.f};

    const int rl = t >> 2, q = t & 3;

    for (int nt = 0; nt < 8; ++nt) {
        const int n0 = ns * 512 + nt * 64;
        // A: desc [128d][64n] -> packed
#pragma unroll
        for (int rr = 0; rr < 2; ++rr) {
            const int row = rr * 64 + rl;
            const float* s = desc + ((size_t)b * DDIM + dblk * 128 + row) * NPOS + n0;
#pragma unroll
            for (int u = 0; u < 4; ++u) {
                const int n = u * 16 + q * 4;
                float4 dv = *(const float4*)&s[n];
                *(uint2*)&Apk[row][n]     = make_uint2(packf(dv.x), packf(dv.y));
                *(uint2*)&Apk[row][n + 2] = make_uint2(packf(dv.z), packf(dv.w));
            }
        }
        // B: P [64k][64n] packed
        {
            const u32* pr = P + ((size_t)b * KCL + rl) * NPOS + n0;
#pragma unroll
            for (int u = 0; u < 4; ++u) {
                const int n = u * 16 + q * 4;
                uint4 v = *(const uint4*)&pr[n];
                *(uint2*)&Pt[rl][n]     = make_uint2(v.x, v.y);
                *(uint2*)&Pt[rl][n + 2] = make_uint2(v.z, v.w);
            }
        }
        __syncthreads();
#pragma unroll
        for (int ks = 0; ks < 2; ++ks) {
            const int kk = ks * 32 + g * 8;
            short8 ah[4], al[4];
#pragma unroll
            for (int mf = 0; mf < 4; ++mf) {
                const u32* ar = &Apk[wm * 64 + mf * 16 + c][kk];
                unpk2(*(const uint2*)&ar[0], *(const uint2*)&ar[2],
                      *(const uint2*)&ar[4], *(const uint2*)&ar[6], ah[mf], al[mf]);
            }
#pragma unroll
            for (int nf = 0; nf < 2; ++nf) {
                const u32* pr2 = &Pt[wk * 32 + nf * 16 + c][kk];
                short8 bh, bl;
                unpk2(*(const uint2*)&pr2[0], *(const uint2*)&pr2[2],
                      *(const uint2*)&pr2[4], *(const uint2*)&pr2[6], bh, bl);
#pragma unroll
                for (int mf = 0; mf < 4; ++mf) {
                    acc[mf][nf] = __builtin_amdgcn_mfma_f32_16x16x32_bf16(ah[mf], bh, acc[mf][nf], 0, 0, 0);
                    acc[mf][nf] = __builtin_amdgcn_mfma_f32_16x16x32_bf16(al[mf], bh, acc[mf][nf], 0, 0, 0);
                    acc[mf][nf] = __builtin_amdgcn_mfma_f32_16x16x32_bf16(ah[mf], bl, acc[mf][nf], 0, 0, 0);
                }
            }
        }
        __syncthreads();
    }
    // C[row=d][col=k] -> part[ns][b][k][d]
#pragma unroll
    for (int nf = 0; nf < 2; ++nf) {
        const int k = wk * 32 + nf * 16 + c;
#pragma unroll
        for (int mf = 0; mf < 4; ++mf) {
            float4 o = make_float4(acc[mf][nf][0], acc[mf][nf][1], acc[mf][nf][2], acc[mf][nf][3]);
            *(float4*)&part[(((size_t)ns * B + b) * KCL + k) * DDIM + dblk * 128 + wm * 64 + mf * 16 + g * 4] = o;
        }
    }
}

// ---------------------------------------------------------------------------
__global__ __launch_bounds__(256) void k_reduce(const float* __restrict__ part,
                                                float* __restrict__ agg, int bkd) {
    size_t e = ((size_t)blockIdx.x * 256 + threadIdx.x) * 4;
    if (e >= (size_t)bkd) return;
    float4 a = *(const float4*)&part[e];
#pragma unroll
    for (int s = 1; s < NSPL; ++s) {
        float4 v = *(const float4*)&part[(size_t)s * bkd + e];
        a.x += v.x; a.y += v.y; a.z += v.z; a.w += v.w;
    }
    *(float4*)&agg[e] = a;
}

// centersT[k][d] <- centers[d][k]
__global__ __launch_bounds__(256) void k_centersT(const float* __restrict__ cen,
                                                  float* __restrict__ cT) {
    __shared__ float Lx[64][65];
    const int dc = blockIdx.x, t = threadIdx.x, r = t >> 2, q = t & 3;
#pragma unroll
    for (int u = 0; u < 4; ++u) {
        const int k = q * 16 + u * 4;
        float4 v = *(const float4*)&cen[((size_t)dc * 64 + r) * KCL + k];
        Lx[r][k] = v.x; Lx[r][k + 1] = v.y; Lx[r][k + 2] = v.z; Lx[r][k + 3] = v.w;
    }
    __syncthreads();
#pragma unroll
    for (int u = 0; u < 4; ++u) {
        const int d = q * 16 + u * 4;
        float4 o = make_float4(Lx[d][r], Lx[d + 1][r], Lx[d + 2][r], Lx[d + 3][r]);
        *(float4*)&cT[(size_t)r * DDIM + dc * 64 + d] = o;
    }
}

__global__ void k_mid(const float* __restrict__ pssum, float* __restrict__ ssum) {
    const int b = blockIdx.x, k = threadIdx.x;
    float a = 0.f;
    for (int nw = 0; nw < 128; ++nw) a += pssum[((size_t)b * 128 + nw) * KCL + k];
    ssum[b * KCL + k] = a;
}

// per-(b,k) column norms on v = agg - cT*ssum; invc = 1/(gn * clamp(cn))
__global__ __launch_bounds__(256) void k_norms(const float* __restrict__ agg,
        const float* __restrict__ cT, const float* __restrict__ ssum,
        float* __restrict__ invc) {
    const int b = blockIdx.x, t = threadIdx.x, w = t >> 6, lane = t & 63;
    __shared__ float cc[64], gp[4];
    float gacc = 0.f;
    for (int i = 0; i < 16; ++i) {
        const int k = w * 16 + i;
        const float sm = ssum[b * KCL + k];
        const float* ar = agg + ((size_t)b * KCL + k) * DDIM + lane * 8;
        const float* cr = cT + (size_t)k * DDIM + lane * 8;
        float sq = 0.f;
#pragma unroll
        for (int j = 0; j < 8; ++j) {
            float v = fmaf(-cr[j], sm, ar[j]);
            sq = fmaf(v, v, sq);
        }
#pragma unroll
        for (int off = 32; off >= 1; off >>= 1) sq += __shfl_xor(sq, off);
        float cl = fmaxf(sqrtf(sq), EPSF);
        if (lane == 0) cc[k] = cl;
        gacc += sq / (cl * cl);
    }
    if (lane == 0) gp[w] = gacc;
    __syncthreads();
    if (t < 64) {
        float gn = fmaxf(sqrtf(gp[0] + gp[1] + gp[2] + gp[3]), EPSF);
        invc[b * KCL + t] = 1.0f / (gn * cc[t]);
    }
}

// out[b][d][k] = (agg[b][k][d] - cT[k][d]*ssum) * invc[b][k]  (LDS transpose)
__global__ __launch_bounds__(256) void k_out(const float* __restrict__ agg,
        const float* __restrict__ cT, const float* __restrict__ ssum,
        const float* __restrict__ invc, float* __restrict__ out) {
    const int dc = blockIdx.x, b = blockIdx.y;
    const int t = threadIdx.x, r = t >> 2, q = t & 3;
    __shared__ float Lx[64][65];
    const float sm = ssum[b * KCL + r], ic = invc[b * KCL + r];
#pragma unroll
    for (int u = 0; u < 4; ++u) {
        const int d = q * 16 + u * 4;
        float4 a = *(const float4*)&agg[((size_t)b * KCL + r) * DDIM + dc * 64 + d];
        float4 cv = *(const float4*)&cT[(size_t)r * DDIM + dc * 64 + d];
        Lx[r][d]     = fmaf(-cv.x, sm, a.x) * ic;
        Lx[r][d + 1] = fmaf(-cv.y, sm, a.y) * ic;
        Lx[r][d + 2] = fmaf(-cv.z, sm, a.z) * ic;
        Lx[r][d + 3] = fmaf(-cv.w, sm, a.w) * ic;
    }
    __syncthreads();
#pragma unroll
    for (int u = 0; u < 4; ++u) {
        const int k = q * 16 + u * 4;
        float4 o = make_float4(Lx[k][r], Lx[k + 1][r], Lx[k + 2][r], Lx[k + 3][r]);
        *(float4*)&out[((size_t)b * DDIM + dc * 64 + r) * KCL + k] = o;
    }
}

// ---------------------------------------------------------------------------
extern "C" void kernel_launch(void* const* d_in, const int* in_sizes, int n_in,
                              void* d_out, int out_size, void* d_ws, size_t ws_size,
                              hipStream_t stream) {
    const float* desc    = (const float*)d_in[0];
    const float* W       = (const float*)d_in[1];
    const float* bias    = (const float*)d_in[2];
    const float* centers = (const float*)d_in[3];
    float* out = (float*)d_out;

    const int B = in_sizes[0] / (DDIM * NPOS);  // 16

    char* ws = (char*)d_ws;
    const size_t pSz    = (size_t)B * KCL * NPOS * 4;        // 16.78 MB (packed u32)
    const size_t partSz = (size_t)NSPL * B * KCL * DDIM * 4; // 16.78 MB
    u32*   P     = (u32*)ws;
    float* part  = (float*)(ws + pSz);
    float* pssum = part;  // aliased: consumed by k_mid before k_agg writes part
    float* agg   = (float*)(ws + pSz + partSz);
    float* cT    = agg + (size_t)B * KCL * DDIM;
    float* ssum  = cT + (size_t)KCL * DDIM;
    float* invc  = ssum + B * KCL;
    u32*   Wp    = (u32*)(invc + B * KCL);                   // 128 KB

    k_wsplit<<<(KCL * DDIM) / 256, 256, 0, stream>>>(W, Wp);
    k_centersT<<<8, 256, 0, stream>>>(centers, cT);
    k_scores<<<dim3(NPOS / 128, B), 256, 0, stream>>>(desc, Wp, bias, P, pssum);
    k_mid<<<B, 64, 0, stream>>>(pssum, ssum);
    k_agg<<<dim3(4, NSPL, B), 256, 0, stream>>>(desc, P, part, B);
    k_reduce<<<(B * KCL * DDIM) / 1024, 256, 0, stream>>>(part, agg, B * KCL * DDIM);
    k_norms<<<B, 256, 0, stream>>>(agg, cT, ssum, invc);
    k_out<<<dim3(8, B), 256, 0, stream>>>(agg, cT, ssum, invc, out);
}

// Round 7
// 123.619 us; speedup vs baseline: 1.0112x; 1.0112x over previous
//
#include <hip/hip_runtime.h>
#include <hip/hip_bf16.h>
#include <math.h>

typedef __attribute__((ext_vector_type(8))) short short8;
typedef __attribute__((ext_vector_type(4))) float f32x4;
typedef unsigned int u32;
typedef unsigned short u16;

#define DDIM 512
#define KCL 64
#define NPOS 4096
#define NSPL 8
#define EPSF 1e-12f

__device__ __forceinline__ u16 f2bf(float x) {
    __hip_bfloat16 h = __float2bfloat16(x);
    return __builtin_bit_cast(u16, h);
}
__device__ __forceinline__ float bf2f(u16 u) {
    unsigned i = ((unsigned)u) << 16;
    return __builtin_bit_cast(float, i);
}
// pack x as bf16(hi) | bf16(residual lo) << 16
__device__ __forceinline__ u32 packf(float x) {
    u16 h = f2bf(x);
    u16 l = f2bf(x - bf2f(h));
    return (u32)h | ((u32)l << 16);
}
// 8 packed u32 (as 4 uint2) -> hi/lo bf16 short8
__device__ __forceinline__ void unpk2(uint2 a0, uint2 a1, uint2 a2, uint2 a3,
                                      short8& hi, short8& lo) {
    uint4 H, L;
    H.x = (a0.x & 0xffffu) | (a0.y << 16);
    L.x = (a0.x >> 16)     | (a0.y & 0xffff0000u);
    H.y = (a1.x & 0xffffu) | (a1.y << 16);
    L.y = (a1.x >> 16)     | (a1.y & 0xffff0000u);
    H.z = (a2.x & 0xffffu) | (a2.y << 16);
    L.z = (a2.x >> 16)     | (a2.y & 0xffff0000u);
    H.w = (a3.x & 0xffffu) | (a3.y << 16);
    L.w = (a3.x >> 16)     | (a3.y & 0xffff0000u);
    hi = __builtin_bit_cast(short8, H);
    lo = __builtin_bit_cast(short8, L);
}

// ---------------------------------------------------------------------------
// W [64][512] fp32 -> packed u32 (bf16 hi | lo<<16), same layout
__global__ __launch_bounds__(256) void k_wsplit(const float* __restrict__ W,
                                                u32* __restrict__ Wp) {
    int i = blockIdx.x * 256 + threadIdx.x;
    Wp[i] = packf(W[i]);
}

// ---------------------------------------------------------------------------
// scores = softmax_k(W @ desc + b) -> P packed u32 [B][K][N], pssum partials.
// grid (64 nblk, B) x 256 thr = 4 waves; block tile [64k x 64n], wave [64k x 16n].
// Split-bf16: hh+lh+hl. W per-dt in LDS (packed copy); desc transposed DT[n][d].
// All LDS patterns at bank floor (derived: stage 2 lanes/bank, frags uniform 4/bank).
__global__ __launch_bounds__(256) void k_scores(const float* __restrict__ desc,
        const u32* __restrict__ Wp, const float* __restrict__ bias,
        u32* __restrict__ P, float* __restrict__ pssum) {
    const int nblk = blockIdx.x, b = blockIdx.y;
    const int t = threadIdx.x;
    const int w = t >> 6, lane = t & 63, c = lane & 15, g = lane >> 4;

    __shared__ u32 Wst[64][66];   // [k][d_local] packed
    __shared__ u32 DT[64][66];    // [n_local][d_local] packed

    f32x4 acc[4];
#pragma unroll
    for (int mf = 0; mf < 4; ++mf) acc[mf] = (f32x4){0.f, 0.f, 0.f, 0.f};

    const int rl = t & 63;        // staging row (all 64 within each wave)
    const int q  = w;             // staging col-chunk = wave id

    for (int dt = 0; dt < 8; ++dt) {
        const int d0 = dt * 64;
        // stage W: copy packed Wp tile [64k][64d] (4 uint4 global, 8 uint2 LDS)
        {
            const u32* wsrc = Wp + (size_t)rl * DDIM + d0 + q * 16;
            uint4 wa = *(const uint4*)&wsrc[0];
            uint4 wb = *(const uint4*)&wsrc[4];
            uint4 wc = *(const uint4*)&wsrc[8];
            uint4 wd = *(const uint4*)&wsrc[12];
            *(uint2*)&Wst[rl][q * 16 + 0]  = make_uint2(wa.x, wa.y);
            *(uint2*)&Wst[rl][q * 16 + 2]  = make_uint2(wa.z, wa.w);
            *(uint2*)&Wst[rl][q * 16 + 4]  = make_uint2(wb.x, wb.y);
            *(uint2*)&Wst[rl][q * 16 + 6]  = make_uint2(wb.z, wb.w);
            *(uint2*)&Wst[rl][q * 16 + 8]  = make_uint2(wc.x, wc.y);
            *(uint2*)&Wst[rl][q * 16 + 10] = make_uint2(wc.z, wc.w);
            *(uint2*)&Wst[rl][q * 16 + 12] = make_uint2(wd.x, wd.y);
            *(uint2*)&Wst[rl][q * 16 + 14] = make_uint2(wd.z, wd.w);
        }
        // stage desc [64d][64n] -> DT[n][d] packed (transpose, scalar b32 writes)
        {
            const float* dsrc = desc + ((size_t)b * DDIM + d0 + rl) * NPOS + nblk * 64 + q * 16;
#pragma unroll
            for (int u = 0; u < 4; ++u) {
                float4 dv = *(const float4*)&dsrc[u * 4];
                const int n = q * 16 + u * 4;
                DT[n + 0][rl] = packf(dv.x);
                DT[n + 1][rl] = packf(dv.y);
                DT[n + 2][rl] = packf(dv.z);
                DT[n + 3][rl] = packf(dv.w);
            }
        }
        __syncthreads();
#pragma unroll
        for (int ks = 0; ks < 2; ++ks) {
            const int kk = ks * 32 + g * 8;
            // B fragment: column n = w*16+c, d = kk..kk+7
            short8 bh, bl;
            {
                const u32* dr = &DT[w * 16 + c][kk];
                unpk2(*(const uint2*)&dr[0], *(const uint2*)&dr[2],
                      *(const uint2*)&dr[4], *(const uint2*)&dr[6], bh, bl);
            }
#pragma unroll
            for (int mf = 0; mf < 4; ++mf) {
                short8 ah, al;
                const u32* ar = &Wst[mf * 16 + c][kk];
                unpk2(*(const uint2*)&ar[0], *(const uint2*)&ar[2],
                      *(const uint2*)&ar[4], *(const uint2*)&ar[6], ah, al);
                acc[mf] = __builtin_amdgcn_mfma_f32_16x16x32_bf16(ah, bh, acc[mf], 0, 0, 0);
                acc[mf] = __builtin_amdgcn_mfma_f32_16x16x32_bf16(al, bh, acc[mf], 0, 0, 0);
                acc[mf] = __builtin_amdgcn_mfma_f32_16x16x32_bf16(ah, bl, acc[mf], 0, 0, 0);
            }
        }
        __syncthreads();
    }

    // epilogue: +bias, softmax over 64 k, pack+store P, ssum partials
#pragma unroll
    for (int mf = 0; mf < 4; ++mf) {
        f32x4 bv = *(const f32x4*)&bias[mf * 16 + g * 4];
        acc[mf] = acc[mf] + bv;
    }
    float m = acc[0][0];
#pragma unroll
    for (int mf = 0; mf < 4; ++mf)
#pragma unroll
        for (int r = 0; r < 4; ++r) m = fmaxf(m, acc[mf][r]);
    m = fmaxf(m, __shfl_xor(m, 16));
    m = fmaxf(m, __shfl_xor(m, 32));
    float s = 0.f;
#pragma unroll
    for (int mf = 0; mf < 4; ++mf)
#pragma unroll
        for (int r = 0; r < 4; ++r) {
            float p = __expf(acc[mf][r] - m);
            acc[mf][r] = p;
            s += p;
        }
    s += __shfl_xor(s, 16);
    s += __shfl_xor(s, 32);
    const float inv = 1.0f / s;
    const int n = nblk * 64 + w * 16 + c;

    float ps[4][4];
#pragma unroll
    for (int mf = 0; mf < 4; ++mf) {
#pragma unroll
        for (int r = 0; r < 4; ++r) {
            float p = acc[mf][r] * inv;
            ps[mf][r] = p;
            const int k = mf * 16 + g * 4 + r;
            P[((size_t)b * KCL + k) * NPOS + n] = packf(p);
        }
    }
#pragma unroll
    for (int mf = 0; mf < 4; ++mf)
#pragma unroll
        for (int r = 0; r < 4; ++r) {
            float v = ps[mf][r];
            v += __shfl_xor(v, 1);
            v += __shfl_xor(v, 2);
            v += __shfl_xor(v, 4);
            v += __shfl_xor(v, 8);
            ps[mf][r] = v;
        }
    if (c == 0) {
#pragma unroll
        for (int mf = 0; mf < 4; ++mf) {
            float4 o = make_float4(ps[mf][0], ps[mf][1], ps[mf][2], ps[mf][3]);
            *(float4*)&pssum[((size_t)b * 256 + nblk * 4 + w) * KCL + mf * 16 + g * 4] = o;
        }
    }
}

// ---------------------------------------------------------------------------
// part[ns][b][k][d] = sum_{n in slice} desc[b][d][n] * P[b][n][k]
// grid (4 dblk, 8 ns, B), 256 thr; tile [128d][64k]. Packed u32 tiles, pitch 66,
// uint2 fragment reads (bank floor).
__global__ __launch_bounds__(256) void k_agg(const float* __restrict__ desc,
        const u32* __restrict__ P, float* __restrict__ part, int B) {
    const int dblk = blockIdx.x, ns = blockIdx.y, b = blockIdx.z;
    const int t = threadIdx.x;
    const int w = t >> 6, lane = t & 63, c = lane & 15, g = lane >> 4;
    const int wm = w & 1, wk = w >> 1;

    __shared__ u32 Apk[128][66];   // desc packed [d][n]
    __shared__ u32 Pt[64][66];     // P packed [k][n]

    f32x4 acc[4][2];
#pragma unroll
    for (int mf = 0; mf < 4; ++mf)
#pragma unroll
        for (int nf = 0; nf < 2; ++nf) acc[mf][nf] = (f32x4){0.f, 0.f, 0.f, 0.f};

    const int rl = t >> 2, q = t & 3;

    for (int nt = 0; nt < 8; ++nt) {
        const int n0 = ns * 512 + nt * 64;
        // A: desc [128d][64n] -> packed
#pragma unroll
        for (int rr = 0; rr < 2; ++rr) {
            const int row = rr * 64 + rl;
            const float* s = desc + ((size_t)b * DDIM + dblk * 128 + row) * NPOS + n0;
#pragma unroll
            for (int u = 0; u < 4; ++u) {
                const int n = u * 16 + q * 4;
                float4 dv = *(const float4*)&s[n];
                *(uint2*)&Apk[row][n]     = make_uint2(packf(dv.x), packf(dv.y));
                *(uint2*)&Apk[row][n + 2] = make_uint2(packf(dv.z), packf(dv.w));
            }
        }
        // B: P [64k][64n] packed
        {
            const u32* pr = P + ((size_t)b * KCL + rl) * NPOS + n0;
#pragma unroll
            for (int u = 0; u < 4; ++u) {
                const int n = u * 16 + q * 4;
                uint4 v = *(const uint4*)&pr[n];
                *(uint2*)&Pt[rl][n]     = make_uint2(v.x, v.y);
                *(uint2*)&Pt[rl][n + 2] = make_uint2(v.z, v.w);
            }
        }
        __syncthreads();
#pragma unroll
        for (int ks = 0; ks < 2; ++ks) {
            const int kk = ks * 32 + g * 8;
            short8 ah[4], al[4];
#pragma unroll
            for (int mf = 0; mf < 4; ++mf) {
                const u32* ar = &Apk[wm * 64 + mf * 16 + c][kk];
                unpk2(*(const uint2*)&ar[0], *(const uint2*)&ar[2],
                      *(const uint2*)&ar[4], *(const uint2*)&ar[6], ah[mf], al[mf]);
            }
#pragma unroll
            for (int nf = 0; nf < 2; ++nf) {
                const u32* pr2 = &Pt[wk * 32 + nf * 16 + c][kk];
                short8 bh, bl;
                unpk2(*(const uint2*)&pr2[0], *(const uint2*)&pr2[2],
                      *(const uint2*)&pr2[4], *(const uint2*)&pr2[6], bh, bl);
#pragma unroll
                for (int mf = 0; mf < 4; ++mf) {
                    acc[mf][nf] = __builtin_amdgcn_mfma_f32_16x16x32_bf16(ah[mf], bh, acc[mf][nf], 0, 0, 0);
                    acc[mf][nf] = __builtin_amdgcn_mfma_f32_16x16x32_bf16(al[mf], bh, acc[mf][nf], 0, 0, 0);
                    acc[mf][nf] = __builtin_amdgcn_mfma_f32_16x16x32_bf16(ah[mf], bl, acc[mf][nf], 0, 0, 0);
                }
            }
        }
        __syncthreads();
    }
    // C[row=d][col=k] -> part[ns][b][k][d]
#pragma unroll
    for (int nf = 0; nf < 2; ++nf) {
        const int k = wk * 32 + nf * 16 + c;
#pragma unroll
        for (int mf = 0; mf < 4; ++mf) {
            float4 o = make_float4(acc[mf][nf][0], acc[mf][nf][1], acc[mf][nf][2], acc[mf][nf][3]);
            *(float4*)&part[(((size_t)ns * B + b) * KCL + k) * DDIM + dblk * 128 + wm * 64 + mf * 16 + g * 4] = o;
        }
    }
}

// ---------------------------------------------------------------------------
__global__ __launch_bounds__(256) void k_reduce(const float* __restrict__ part,
                                                float* __restrict__ agg, int bkd) {
    size_t e = ((size_t)blockIdx.x * 256 + threadIdx.x) * 4;
    if (e >= (size_t)bkd) return;
    float4 a = *(const float4*)&part[e];
#pragma unroll
    for (int s = 1; s < NSPL; ++s) {
        float4 v = *(const float4*)&part[(size_t)s * bkd + e];
        a.x += v.x; a.y += v.y; a.z += v.z; a.w += v.w;
    }
    *(float4*)&agg[e] = a;
}

// centersT[k][d] <- centers[d][k]
__global__ __launch_bounds__(256) void k_centersT(const float* __restrict__ cen,
                                                  float* __restrict__ cT) {
    __shared__ float Lx[64][65];
    const int dc = blockIdx.x, t = threadIdx.x, r = t >> 2, q = t & 3;
#pragma unroll
    for (int u = 0; u < 4; ++u) {
        const int k = q * 16 + u * 4;
        float4 v = *(const float4*)&cen[((size_t)dc * 64 + r) * KCL + k];
        Lx[r][k] = v.x; Lx[r][k + 1] = v.y; Lx[r][k + 2] = v.z; Lx[r][k + 3] = v.w;
    }
    __syncthreads();
#pragma unroll
    for (int u = 0; u < 4; ++u) {
        const int d = q * 16 + u * 4;
        float4 o = make_float4(Lx[d][r], Lx[d + 1][r], Lx[d + 2][r], Lx[d + 3][r]);
        *(float4*)&cT[(size_t)r * DDIM + dc * 64 + d] = o;
    }
}

__global__ void k_mid(const float* __restrict__ pssum, float* __restrict__ ssum) {
    const int b = blockIdx.x, k = threadIdx.x;
    float a = 0.f;
    for (int nw = 0; nw < 256; ++nw) a += pssum[((size_t)b * 256 + nw) * KCL + k];
    ssum[b * KCL + k] = a;
}

// per-(b,k) column norms on v = agg - cT*ssum; invc = 1/(gn * clamp(cn))
__global__ __launch_bounds__(256) void k_norms(const float* __restrict__ agg,
        const float* __restrict__ cT, const float* __restrict__ ssum,
        float* __restrict__ invc) {
    const int b = blockIdx.x, t = threadIdx.x, w = t >> 6, lane = t & 63;
    __shared__ float cc[64], gp[4];
    float gacc = 0.f;
    for (int i = 0; i < 16; ++i) {
        const int k = w * 16 + i;
        const float sm = ssum[b * KCL + k];
        const float* ar = agg + ((size_t)b * KCL + k) * DDIM + lane * 8;
        const float* cr = cT + (size_t)k * DDIM + lane * 8;
        float sq = 0.f;
#pragma unroll
        for (int j = 0; j < 8; ++j) {
            float v = fmaf(-cr[j], sm, ar[j]);
            sq = fmaf(v, v, sq);
        }
#pragma unroll
        for (int off = 32; off >= 1; off >>= 1) sq += __shfl_xor(sq, off);
        float cl = fmaxf(sqrtf(sq), EPSF);
        if (lane == 0) cc[k] = cl;
        gacc += sq / (cl * cl);
    }
    if (lane == 0) gp[w] = gacc;
    __syncthreads();
    if (t < 64) {
        float gn = fmaxf(sqrtf(gp[0] + gp[1] + gp[2] + gp[3]), EPSF);
        invc[b * KCL + t] = 1.0f / (gn * cc[t]);
    }
}

// out[b][d][k] = (agg[b][k][d] - cT[k][d]*ssum) * invc[b][k]  (LDS transpose)
__global__ __launch_bounds__(256) void k_out(const float* __restrict__ agg,
        const float* __restrict__ cT, const float* __restrict__ ssum,
        const float* __restrict__ invc, float* __restrict__ out) {
    const int dc = blockIdx.x, b = blockIdx.y;
    const int t = threadIdx.x, r = t >> 2, q = t & 3;
    __shared__ float Lx[64][65];
    const float sm = ssum[b * KCL + r], ic = invc[b * KCL + r];
#pragma unroll
    for (int u = 0; u < 4; ++u) {
        const int d = q * 16 + u * 4;
        float4 a = *(const float4*)&agg[((size_t)b * KCL + r) * DDIM + dc * 64 + d];
        float4 cv = *(const float4*)&cT[(size_t)r * DDIM + dc * 64 + d];
        Lx[r][d]     = fmaf(-cv.x, sm, a.x) * ic;
        Lx[r][d + 1] = fmaf(-cv.y, sm, a.y) * ic;
        Lx[r][d + 2] = fmaf(-cv.z, sm, a.z) * ic;
        Lx[r][d + 3] = fmaf(-cv.w, sm, a.w) * ic;
    }
    __syncthreads();
#pragma unroll
    for (int u = 0; u < 4; ++u) {
        const int k = q * 16 + u * 4;
        float4 o = make_float4(Lx[k][r], Lx[k + 1][r], Lx[k + 2][r], Lx[k + 3][r]);
        *(float4*)&out[((size_t)b * DDIM + dc * 64 + r) * KCL + k] = o;
    }
}

// ---------------------------------------------------------------------------
extern "C" void kernel_launch(void* const* d_in, const int* in_sizes, int n_in,
                              void* d_out, int out_size, void* d_ws, size_t ws_size,
                              hipStream_t stream) {
    const float* desc    = (const float*)d_in[0];
    const float* W       = (const float*)d_in[1];
    const float* bias    = (const float*)d_in[2];
    const float* centers = (const float*)d_in[3];
    float* out = (float*)d_out;

    const int B = in_sizes[0] / (DDIM * NPOS);  // 16

    char* ws = (char*)d_ws;
    const size_t pSz    = (size_t)B * KCL * NPOS * 4;        // 16.78 MB (packed u32)
    const size_t partSz = (size_t)NSPL * B * KCL * DDIM * 4; // 16.78 MB
    u32*   P     = (u32*)ws;
    float* part  = (float*)(ws + pSz);
    float* pssum = part;  // aliased: consumed by k_mid before k_agg writes part
    float* agg   = (float*)(ws + pSz + partSz);
    float* cT    = agg + (size_t)B * KCL * DDIM;
    float* ssum  = cT + (size_t)KCL * DDIM;
    float* invc  = ssum + B * KCL;
    u32*   Wp    = (u32*)(invc + B * KCL);                   // 128 KB

    k_wsplit<<<(KCL * DDIM) / 256, 256, 0, stream>>>(W, Wp);
    k_centersT<<<8, 256, 0, stream>>>(centers, cT);
    k_scores<<<dim3(NPOS / 64, B), 256, 0, stream>>>(desc, Wp, bias, P, pssum);
    k_mid<<<B, 64, 0, stream>>>(pssum, ssum);
    k_agg<<<dim3(4, NSPL, B), 256, 0, stream>>>(desc, P, part, B);
    k_reduce<<<(B * KCL * DDIM) / 1024, 256, 0, stream>>>(part, agg, B * KCL * DDIM);
    k_norms<<<B, 256, 0, stream>>>(agg, cT, ssum, invc);
    k_out<<<dim3(8, B), 256, 0, stream>>>(agg, cT, ssum, invc, out);
}

// Round 8
// 93.737 us; speedup vs baseline: 1.3335x; 1.3188x over previous
//
#include <hip/hip_runtime.h>
#include <hip/hip_bf16.h>
#include <math.h>

typedef __attribute__((ext_vector_type(8))) short short8;
typedef __attribute__((ext_vector_type(4))) float f32x4;
typedef __attribute__((ext_vector_type(4))) unsigned short u16x4;
typedef unsigned int u32;
typedef unsigned short u16;

#define DDIM 512
#define KCL 64
#define NPOS 4096
#define NSPL 8
#define EPSF 1e-12f

__device__ __forceinline__ u16 f2bf(float x) {
    __hip_bfloat16 h = __float2bfloat16(x);
    return __builtin_bit_cast(u16, h);
}
__device__ __forceinline__ float bf2f(u16 u) {
    unsigned i = ((unsigned)u) << 16;
    return __builtin_bit_cast(float, i);
}
// pack x as bf16(hi) | bf16(residual lo) << 16
__device__ __forceinline__ u32 packf(float x) {
    u16 h = f2bf(x);
    u16 l = f2bf(x - bf2f(h));
    return (u32)h | ((u32)l << 16);
}
// 8 packed u32 (as 4 uint2) -> hi/lo bf16 short8
__device__ __forceinline__ void unpk2(uint2 a0, uint2 a1, uint2 a2, uint2 a3,
                                      short8& hi, short8& lo) {
    uint4 H, L;
    H.x = (a0.x & 0xffffu) | (a0.y << 16);
    L.x = (a0.x >> 16)     | (a0.y & 0xffff0000u);
    H.y = (a1.x & 0xffffu) | (a1.y << 16);
    L.y = (a1.x >> 16)     | (a1.y & 0xffff0000u);
    H.z = (a2.x & 0xffffu) | (a2.y << 16);
    L.z = (a2.x >> 16)     | (a2.y & 0xffff0000u);
    H.w = (a3.x & 0xffffu) | (a3.y << 16);
    L.w = (a3.x >> 16)     | (a3.y & 0xffff0000u);
    hi = __builtin_bit_cast(short8, H);
    lo = __builtin_bit_cast(short8, L);
}

// ---------------------------------------------------------------------------
// scores = softmax_k(W @ desc + b) -> P packed u32 [B][K][N], pssum partials.
// grid (32 nblk, B), 256 thr = 4 waves x (64k x 32n). Split-bf16 hh+lh+hl.
// T14 async-STAGE split: dt+1 global loads issued before dt's compute phase.
__global__ __launch_bounds__(256) void k_scores(const float* __restrict__ desc,
        const float* __restrict__ W, const float* __restrict__ bias,
        u32* __restrict__ P, float* __restrict__ pssum) {
    const int nblk = blockIdx.x, b = blockIdx.y;
    const int t = threadIdx.x;
    const int w = t >> 6, lane = t & 63, c = lane & 15, g = lane >> 4;

    __shared__ u16 Wh[64][72], Wl[64][72];     // [k][d] pitch 72
    __shared__ u16 Dh[64][130], Dl[64][130];   // [d][n] pitch 130

    f32x4 acc[4][2];
#pragma unroll
    for (int mf = 0; mf < 4; ++mf)
#pragma unroll
        for (int nf = 0; nf < 2; ++nf) acc[mf][nf] = (f32x4){0.f, 0.f, 0.f, 0.f};

    const int rl = t >> 2, q = t & 3;

    // register staging buffers (current + next)
    float4 dcur[8], wcur[4], dnxt[8], wnxt[4];
    {
        const float* dsrc = desc + ((size_t)b * DDIM + rl) * NPOS + nblk * 128;
        const float* wsrc = W + (size_t)rl * DDIM;
#pragma unroll
        for (int u = 0; u < 8; ++u) dcur[u] = *(const float4*)&dsrc[u * 16 + q * 4];
#pragma unroll
        for (int u = 0; u < 4; ++u) wcur[u] = *(const float4*)&wsrc[u * 16 + q * 4];
    }

#pragma unroll
    for (int dt = 0; dt < 8; ++dt) {
        // write phase: pack current regs -> LDS
#pragma unroll
        for (int u = 0; u < 4; ++u) {
            const int dd = u * 16 + q * 4;
            float4 wv = wcur[u];
            u16 h0 = f2bf(wv.x), h1 = f2bf(wv.y), h2 = f2bf(wv.z), h3 = f2bf(wv.w);
            *(u16x4*)&Wh[rl][dd] = (u16x4){h0, h1, h2, h3};
            *(u16x4*)&Wl[rl][dd] = (u16x4){f2bf(wv.x - bf2f(h0)), f2bf(wv.y - bf2f(h1)),
                                           f2bf(wv.z - bf2f(h2)), f2bf(wv.w - bf2f(h3))};
        }
#pragma unroll
        for (int u = 0; u < 8; ++u) {
            const int n = u * 16 + q * 4;
            float4 dv = dcur[u];
            u16 h0 = f2bf(dv.x), h1 = f2bf(dv.y), h2 = f2bf(dv.z), h3 = f2bf(dv.w);
            *(u16x4*)&Dh[rl][n] = (u16x4){h0, h1, h2, h3};
            *(u16x4*)&Dl[rl][n] =
                (u16x4){f2bf(dv.x - bf2f(h0)), f2bf(dv.y - bf2f(h1)),
                        f2bf(dv.z - bf2f(h2)), f2bf(dv.w - bf2f(h3))};
        }
        __syncthreads();
        // prefetch dt+1 (in flight across the compute phase)
        if (dt < 7) {
            const int d0 = (dt + 1) * 64;
            const float* dsrc = desc + ((size_t)b * DDIM + d0 + rl) * NPOS + nblk * 128;
            const float* wsrc = W + (size_t)rl * DDIM + d0;
#pragma unroll
            for (int u = 0; u < 8; ++u) dnxt[u] = *(const float4*)&dsrc[u * 16 + q * 4];
#pragma unroll
            for (int u = 0; u < 4; ++u) wnxt[u] = *(const float4*)&wsrc[u * 16 + q * 4];
        }
        // compute phase
#pragma unroll
        for (int ks = 0; ks < 2; ++ks) {
            const int kk = ks * 32 + g * 8;
            short8 ah[4], al[4];
#pragma unroll
            for (int mf = 0; mf < 4; ++mf) {
                ah[mf] = *(const short8*)&Wh[mf * 16 + c][kk];
                al[mf] = *(const short8*)&Wl[mf * 16 + c][kk];
            }
#pragma unroll
            for (int nf = 0; nf < 2; ++nf) {
                const int nc = w * 32 + nf * 16 + c;
                short8 bh, bl;
#pragma unroll
                for (int j = 0; j < 8; ++j) {
                    bh[j] = (short)Dh[kk + j][nc];
                    bl[j] = (short)Dl[kk + j][nc];
                }
#pragma unroll
                for (int mf = 0; mf < 4; ++mf) {
                    acc[mf][nf] = __builtin_amdgcn_mfma_f32_16x16x32_bf16(ah[mf], bh, acc[mf][nf], 0, 0, 0);
                    acc[mf][nf] = __builtin_amdgcn_mfma_f32_16x16x32_bf16(al[mf], bh, acc[mf][nf], 0, 0, 0);
                    acc[mf][nf] = __builtin_amdgcn_mfma_f32_16x16x32_bf16(ah[mf], bl, acc[mf][nf], 0, 0, 0);
                }
            }
        }
        __syncthreads();
        if (dt < 7) {
#pragma unroll
            for (int u = 0; u < 8; ++u) dcur[u] = dnxt[u];
#pragma unroll
            for (int u = 0; u < 4; ++u) wcur[u] = wnxt[u];
        }
    }

    // epilogue: +bias, softmax over 64 k, pack+store P, ssum partials
#pragma unroll
    for (int mf = 0; mf < 4; ++mf) {
        f32x4 bv = *(const f32x4*)&bias[mf * 16 + g * 4];
#pragma unroll
        for (int nf = 0; nf < 2; ++nf) acc[mf][nf] = acc[mf][nf] + bv;
    }

    float ps[4][4];
#pragma unroll
    for (int mf = 0; mf < 4; ++mf)
#pragma unroll
        for (int r = 0; r < 4; ++r) ps[mf][r] = 0.f;

#pragma unroll
    for (int nf = 0; nf < 2; ++nf) {
        float m = acc[0][nf][0];
#pragma unroll
        for (int mf = 0; mf < 4; ++mf)
#pragma unroll
            for (int r = 0; r < 4; ++r) m = fmaxf(m, acc[mf][nf][r]);
        m = fmaxf(m, __shfl_xor(m, 16));
        m = fmaxf(m, __shfl_xor(m, 32));
        float s = 0.f;
#pragma unroll
        for (int mf = 0; mf < 4; ++mf)
#pragma unroll
            for (int r = 0; r < 4; ++r) {
                float p = __expf(acc[mf][nf][r] - m);
                acc[mf][nf][r] = p;
                s += p;
            }
        s += __shfl_xor(s, 16);
        s += __shfl_xor(s, 32);
        const float inv = 1.0f / s;
        const int n = nblk * 128 + w * 32 + nf * 16 + c;
#pragma unroll
        for (int mf = 0; mf < 4; ++mf) {
#pragma unroll
            for (int r = 0; r < 4; ++r) {
                float p = acc[mf][nf][r] * inv;
                ps[mf][r] += p;
                const int k = mf * 16 + g * 4 + r;
                P[((size_t)b * KCL + k) * NPOS + n] = packf(p);
            }
        }
    }
#pragma unroll
    for (int mf = 0; mf < 4; ++mf)
#pragma unroll
        for (int r = 0; r < 4; ++r) {
            float v = ps[mf][r];
            v += __shfl_xor(v, 1);
            v += __shfl_xor(v, 2);
            v += __shfl_xor(v, 4);
            v += __shfl_xor(v, 8);
            ps[mf][r] = v;
        }
    if (c == 0) {
#pragma unroll
        for (int mf = 0; mf < 4; ++mf) {
            float4 o = make_float4(ps[mf][0], ps[mf][1], ps[mf][2], ps[mf][3]);
            *(float4*)&pssum[((size_t)b * 128 + nblk * 4 + w) * KCL + mf * 16 + g * 4] = o;
        }
    }
}

// ---------------------------------------------------------------------------
__global__ void k_mid(const float* __restrict__ pssum, float* __restrict__ ssum) {
    const int b = blockIdx.x, k = threadIdx.x;
    float a = 0.f;
    for (int nw = 0; nw < 128; ++nw) a += pssum[((size_t)b * 128 + nw) * KCL + k];
    ssum[b * KCL + k] = a;
}

// ---------------------------------------------------------------------------
// part[ns][b][k][d] = sum_{n in slice} desc[b][d][n] * P[b][n][k]
// grid (4 dblk, 8 ns, B), 256 thr; tile [128d][64k]. Packed u32 tiles, pitch 66.
__global__ __launch_bounds__(256) void k_agg(const float* __restrict__ desc,
        const u32* __restrict__ P, float* __restrict__ part, int B) {
    const int dblk = blockIdx.x, ns = blockIdx.y, b = blockIdx.z;
    const int t = threadIdx.x;
    const int w = t >> 6, lane = t & 63, c = lane & 15, g = lane >> 4;
    const int wm = w & 1, wk = w >> 1;

    __shared__ u32 Apk[128][66];   // desc packed [d][n]
    __shared__ u32 Pt[64][66];     // P packed [k][n]

    f32x4 acc[4][2];
#pragma unroll
    for (int mf = 0; mf < 4; ++mf)
#pragma unroll
        for (int nf = 0; nf < 2; ++nf) acc[mf][nf] = (f32x4){0.f, 0.f, 0.f, 0.f};

    const int rl = t >> 2, q = t & 3;

    for (int nt = 0; nt < 8; ++nt) {
        const int n0 = ns * 512 + nt * 64;
#pragma unroll
        for (int rr = 0; rr < 2; ++rr) {
            const int row = rr * 64 + rl;
            const float* s = desc + ((size_t)b * DDIM + dblk * 128 + row) * NPOS + n0;
#pragma unroll
            for (int u = 0; u < 4; ++u) {
                const int n = u * 16 + q * 4;
                float4 dv = *(const float4*)&s[n];
                *(uint2*)&Apk[row][n]     = make_uint2(packf(dv.x), packf(dv.y));
                *(uint2*)&Apk[row][n + 2] = make_uint2(packf(dv.z), packf(dv.w));
            }
        }
        {
            const u32* pr = P + ((size_t)b * KCL + rl) * NPOS + n0;
#pragma unroll
            for (int u = 0; u < 4; ++u) {
                const int n = u * 16 + q * 4;
                uint4 v = *(const uint4*)&pr[n];
                *(uint2*)&Pt[rl][n]     = make_uint2(v.x, v.y);
                *(uint2*)&Pt[rl][n + 2] = make_uint2(v.z, v.w);
            }
        }
        __syncthreads();
#pragma unroll
        for (int ks = 0; ks < 2; ++ks) {
            const int kk = ks * 32 + g * 8;
            short8 ah[4], al[4];
#pragma unroll
            for (int mf = 0; mf < 4; ++mf) {
                const u32* ar = &Apk[wm * 64 + mf * 16 + c][kk];
                unpk2(*(const uint2*)&ar[0], *(const uint2*)&ar[2],
                      *(const uint2*)&ar[4], *(const uint2*)&ar[6], ah[mf], al[mf]);
            }
#pragma unroll
            for (int nf = 0; nf < 2; ++nf) {
                const u32* pr2 = &Pt[wk * 32 + nf * 16 + c][kk];
                short8 bh, bl;
                unpk2(*(const uint2*)&pr2[0], *(const uint2*)&pr2[2],
                      *(const uint2*)&pr2[4], *(const uint2*)&pr2[6], bh, bl);
#pragma unroll
                for (int mf = 0; mf < 4; ++mf) {
                    acc[mf][nf] = __builtin_amdgcn_mfma_f32_16x16x32_bf16(ah[mf], bh, acc[mf][nf], 0, 0, 0);
                    acc[mf][nf] = __builtin_amdgcn_mfma_f32_16x16x32_bf16(al[mf], bh, acc[mf][nf], 0, 0, 0);
                    acc[mf][nf] = __builtin_amdgcn_mfma_f32_16x16x32_bf16(ah[mf], bl, acc[mf][nf], 0, 0, 0);
                }
            }
        }
        __syncthreads();
    }
#pragma unroll
    for (int nf = 0; nf < 2; ++nf) {
        const int k = wk * 32 + nf * 16 + c;
#pragma unroll
        for (int mf = 0; mf < 4; ++mf) {
            float4 o = make_float4(acc[mf][nf][0], acc[mf][nf][1], acc[mf][nf][2], acc[mf][nf][3]);
            *(float4*)&part[(((size_t)ns * B + b) * KCL + k) * DDIM + dblk * 128 + wm * 64 + mf * 16 + g * 4] = o;
        }
    }
}

// ---------------------------------------------------------------------------
// finalA: per (b,k): reduce 8 partials, subtract centers*ssum, write centered v
// into agg[b][k][d], and per-column sum-of-squares into cn2[b][k].
// grid B*K blocks, 256 thr (2 d each).
__global__ __launch_bounds__(256) void k_finalA(const float* __restrict__ part,
        const float* __restrict__ centers, const float* __restrict__ ssum,
        float* __restrict__ agg, float* __restrict__ cn2, int B) {
    const int bk = blockIdx.x;
    const int b = bk >> 6, k = bk & 63;
    const int t = threadIdx.x;
    const float sm = ssum[bk];
    const int d = t * 2;

    float2 a = make_float2(0.f, 0.f);
#pragma unroll
    for (int ns = 0; ns < NSPL; ++ns) {
        float2 v = *(const float2*)&part[(((size_t)ns * B + b) * KCL + k) * DDIM + d];
        a.x += v.x; a.y += v.y;
    }
    float c0 = centers[(size_t)d * KCL + k];
    float c1 = centers[(size_t)(d + 1) * KCL + k];
    float v0 = fmaf(-c0, sm, a.x);
    float v1 = fmaf(-c1, sm, a.y);
    *(float2*)&agg[((size_t)b * KCL + k) * DDIM + d] = make_float2(v0, v1);

    float sq = fmaf(v0, v0, v1 * v1);
#pragma unroll
    for (int off = 32; off >= 1; off >>= 1) sq += __shfl_xor(sq, off);
    __shared__ float red[4];
    if ((t & 63) == 0) red[t >> 6] = sq;
    __syncthreads();
    if (t == 0) cn2[bk] = red[0] + red[1] + red[2] + red[3];
}

// ---------------------------------------------------------------------------
// finalB: gn per batch from cn2; out[b][d][k] = agg[b][k][d] / (gn*cl_k)
// via LDS transpose. grid (8 dc, B), 256 thr.
__global__ __launch_bounds__(256) void k_finalB(const float* __restrict__ agg,
        const float* __restrict__ cn2, float* __restrict__ out) {
    const int dc = blockIdx.x, b = blockIdx.y;
    const int t = threadIdx.x, r = t >> 2, q = t & 3;
    __shared__ float Lx[64][65];
    __shared__ float invs[64];

    if (t < 64) {
        float c2 = cn2[b * KCL + t];
        float cl = fmaxf(sqrtf(c2), EPSF);
        float tk = c2 / (cl * cl);
        float s = tk;
#pragma unroll
        for (int off = 32; off >= 1; off >>= 1) s += __shfl_xor(s, off);
        float gn = fmaxf(sqrtf(s), EPSF);
        invs[t] = 1.0f / (gn * cl);
    }
    __syncthreads();
    const float ic = invs[r];
#pragma unroll
    for (int u = 0; u < 4; ++u) {
        const int d = q * 16 + u * 4;
        float4 a = *(const float4*)&agg[((size_t)b * KCL + r) * DDIM + dc * 64 + d];
        Lx[r][d]     = a.x * ic;
        Lx[r][d + 1] = a.y * ic;
        Lx[r][d + 2] = a.z * ic;
        Lx[r][d + 3] = a.w * ic;
    }
    __syncthreads();
#pragma unroll
    for (int u = 0; u < 4; ++u) {
        const int k = q * 16 + u * 4;
        float4 o = make_float4(Lx[k][r], Lx[k + 1][r], Lx[k + 2][r], Lx[k + 3][r]);
        *(float4*)&out[((size_t)b * DDIM + dc * 64 + r) * KCL + k] = o;
    }
}

// ---------------------------------------------------------------------------
extern "C" void kernel_launch(void* const* d_in, const int* in_sizes, int n_in,
                              void* d_out, int out_size, void* d_ws, size_t ws_size,
                              hipStream_t stream) {
    const float* desc    = (const float*)d_in[0];
    const float* W       = (const float*)d_in[1];
    const float* bias    = (const float*)d_in[2];
    const float* centers = (const float*)d_in[3];
    float* out = (float*)d_out;

    const int B = in_sizes[0] / (DDIM * NPOS);  // 16

    char* ws = (char*)d_ws;
    const size_t pSz    = (size_t)B * KCL * NPOS * 4;        // 16.78 MB (packed u32)
    const size_t partSz = (size_t)NSPL * B * KCL * DDIM * 4; // 16.78 MB
    u32*   P     = (u32*)ws;
    float* part  = (float*)(ws + pSz);
    float* pssum = part;  // aliased: consumed by k_mid before k_agg writes part
    float* agg   = (float*)(ws + pSz + partSz);
    float* ssum  = agg + (size_t)B * KCL * DDIM;
    float* cn2   = ssum + B * KCL;

    k_scores<<<dim3(NPOS / 128, B), 256, 0, stream>>>(desc, W, bias, P, pssum);
    k_mid<<<B, 64, 0, stream>>>(pssum, ssum);
    k_agg<<<dim3(4, NSPL, B), 256, 0, stream>>>(desc, P, part, B);
    k_finalA<<<B * KCL, 256, 0, stream>>>(part, centers, ssum, agg, cn2, B);
    k_finalB<<<dim3(8, B), 256, 0, stream>>>(agg, cn2, out);
}

// Round 9
// 81.694 us; speedup vs baseline: 1.5301x; 1.1474x over previous
//
#include <hip/hip_runtime.h>
#include <hip/hip_bf16.h>
#include <math.h>

typedef __attribute__((ext_vector_type(8))) short short8;
typedef __attribute__((ext_vector_type(4))) float f32x4;
typedef __attribute__((ext_vector_type(4))) unsigned short u16x4;
typedef unsigned int u32;
typedef unsigned short u16;

#define DDIM 512
#define KCL 64
#define NPOS 4096
#define NSPL 8
#define EPSF 1e-12f

__device__ __forceinline__ u16 f2bf(float x) {
    __hip_bfloat16 h = __float2bfloat16(x);
    return __builtin_bit_cast(u16, h);
}
__device__ __forceinline__ float bf2f(u16 u) {
    unsigned i = ((unsigned)u) << 16;
    return __builtin_bit_cast(float, i);
}
// pack x as bf16(hi) | bf16(residual lo) << 16
__device__ __forceinline__ u32 packf(float x) {
    u16 h = f2bf(x);
    u16 l = f2bf(x - bf2f(h));
    return (u32)h | ((u32)l << 16);
}
// 8 packed u32 (as 4 uint2) -> hi/lo bf16 short8
__device__ __forceinline__ void unpk2(uint2 a0, uint2 a1, uint2 a2, uint2 a3,
                                      short8& hi, short8& lo) {
    uint4 H, L;
    H.x = (a0.x & 0xffffu) | (a0.y << 16);
    L.x = (a0.x >> 16)     | (a0.y & 0xffff0000u);
    H.y = (a1.x & 0xffffu) | (a1.y << 16);
    L.y = (a1.x >> 16)     | (a1.y & 0xffff0000u);
    H.z = (a2.x & 0xffffu) | (a2.y << 16);
    L.z = (a2.x >> 16)     | (a2.y & 0xffff0000u);
    H.w = (a3.x & 0xffffu) | (a3.y << 16);
    L.w = (a3.x >> 16)     | (a3.y & 0xffff0000u);
    hi = __builtin_bit_cast(short8, H);
    lo = __builtin_bit_cast(short8, L);
}

// ---------------------------------------------------------------------------
// scores = softmax_k(W @ desc + b) -> P packed u32 [B][K][N], pssum partials.
// grid (32 nblk, B), 256 thr = 4 waves x (64k x 32n). Split-bf16 hh+lh+hl.
// T14 async-STAGE split: dt+1 global loads issued before dt's compute phase.
__global__ __launch_bounds__(256) void k_scores(const float* __restrict__ desc,
        const float* __restrict__ W, const float* __restrict__ bias,
        u32* __restrict__ P, float* __restrict__ pssum) {
    const int nblk = blockIdx.x, b = blockIdx.y;
    const int t = threadIdx.x;
    const int w = t >> 6, lane = t & 63, c = lane & 15, g = lane >> 4;

    __shared__ u16 Wh[64][72], Wl[64][72];     // [k][d] pitch 72
    __shared__ u16 Dh[64][130], Dl[64][130];   // [d][n] pitch 130

    f32x4 acc[4][2];
#pragma unroll
    for (int mf = 0; mf < 4; ++mf)
#pragma unroll
        for (int nf = 0; nf < 2; ++nf) acc[mf][nf] = (f32x4){0.f, 0.f, 0.f, 0.f};

    const int rl = t >> 2, q = t & 3;

    // register staging buffers (current + next)
    float4 dcur[8], wcur[4], dnxt[8], wnxt[4];
    {
        const float* dsrc = desc + ((size_t)b * DDIM + rl) * NPOS + nblk * 128;
        const float* wsrc = W + (size_t)rl * DDIM;
#pragma unroll
        for (int u = 0; u < 8; ++u) dcur[u] = *(const float4*)&dsrc[u * 16 + q * 4];
#pragma unroll
        for (int u = 0; u < 4; ++u) wcur[u] = *(const float4*)&wsrc[u * 16 + q * 4];
    }

#pragma unroll
    for (int dt = 0; dt < 8; ++dt) {
        // write phase: pack current regs -> LDS
#pragma unroll
        for (int u = 0; u < 4; ++u) {
            const int dd = u * 16 + q * 4;
            float4 wv = wcur[u];
            u16 h0 = f2bf(wv.x), h1 = f2bf(wv.y), h2 = f2bf(wv.z), h3 = f2bf(wv.w);
            *(u16x4*)&Wh[rl][dd] = (u16x4){h0, h1, h2, h3};
            *(u16x4*)&Wl[rl][dd] = (u16x4){f2bf(wv.x - bf2f(h0)), f2bf(wv.y - bf2f(h1)),
                                           f2bf(wv.z - bf2f(h2)), f2bf(wv.w - bf2f(h3))};
        }
#pragma unroll
        for (int u = 0; u < 8; ++u) {
            const int n = u * 16 + q * 4;
            float4 dv = dcur[u];
            u16 h0 = f2bf(dv.x), h1 = f2bf(dv.y), h2 = f2bf(dv.z), h3 = f2bf(dv.w);
            *(u16x4*)&Dh[rl][n] = (u16x4){h0, h1, h2, h3};
            *(u16x4*)&Dl[rl][n] =
                (u16x4){f2bf(dv.x - bf2f(h0)), f2bf(dv.y - bf2f(h1)),
                        f2bf(dv.z - bf2f(h2)), f2bf(dv.w - bf2f(h3))};
        }
        __syncthreads();
        // prefetch dt+1 (in flight across the compute phase)
        if (dt < 7) {
            const int d0 = (dt + 1) * 64;
            const float* dsrc = desc + ((size_t)b * DDIM + d0 + rl) * NPOS + nblk * 128;
            const float* wsrc = W + (size_t)rl * DDIM + d0;
#pragma unroll
            for (int u = 0; u < 8; ++u) dnxt[u] = *(const float4*)&dsrc[u * 16 + q * 4];
#pragma unroll
            for (int u = 0; u < 4; ++u) wnxt[u] = *(const float4*)&wsrc[u * 16 + q * 4];
        }
        // compute phase
#pragma unroll
        for (int ks = 0; ks < 2; ++ks) {
            const int kk = ks * 32 + g * 8;
            short8 ah[4], al[4];
#pragma unroll
            for (int mf = 0; mf < 4; ++mf) {
                ah[mf] = *(const short8*)&Wh[mf * 16 + c][kk];
                al[mf] = *(const short8*)&Wl[mf * 16 + c][kk];
            }
#pragma unroll
            for (int nf = 0; nf < 2; ++nf) {
                const int nc = w * 32 + nf * 16 + c;
                short8 bh, bl;
#pragma unroll
                for (int j = 0; j < 8; ++j) {
                    bh[j] = (short)Dh[kk + j][nc];
                    bl[j] = (short)Dl[kk + j][nc];
                }
#pragma unroll
                for (int mf = 0; mf < 4; ++mf) {
                    acc[mf][nf] = __builtin_amdgcn_mfma_f32_16x16x32_bf16(ah[mf], bh, acc[mf][nf], 0, 0, 0);
                    acc[mf][nf] = __builtin_amdgcn_mfma_f32_16x16x32_bf16(al[mf], bh, acc[mf][nf], 0, 0, 0);
                    acc[mf][nf] = __builtin_amdgcn_mfma_f32_16x16x32_bf16(ah[mf], bl, acc[mf][nf], 0, 0, 0);
                }
            }
        }
        __syncthreads();
        if (dt < 7) {
#pragma unroll
            for (int u = 0; u < 8; ++u) dcur[u] = dnxt[u];
#pragma unroll
            for (int u = 0; u < 4; ++u) wcur[u] = wnxt[u];
        }
    }

    // epilogue: +bias, softmax over 64 k, pack+store P, ssum partials
#pragma unroll
    for (int mf = 0; mf < 4; ++mf) {
        f32x4 bv = *(const f32x4*)&bias[mf * 16 + g * 4];
#pragma unroll
        for (int nf = 0; nf < 2; ++nf) acc[mf][nf] = acc[mf][nf] + bv;
    }

    float ps[4][4];
#pragma unroll
    for (int mf = 0; mf < 4; ++mf)
#pragma unroll
        for (int r = 0; r < 4; ++r) ps[mf][r] = 0.f;

#pragma unroll
    for (int nf = 0; nf < 2; ++nf) {
        float m = acc[0][nf][0];
#pragma unroll
        for (int mf = 0; mf < 4; ++mf)
#pragma unroll
            for (int r = 0; r < 4; ++r) m = fmaxf(m, acc[mf][nf][r]);
        m = fmaxf(m, __shfl_xor(m, 16));
        m = fmaxf(m, __shfl_xor(m, 32));
        float s = 0.f;
#pragma unroll
        for (int mf = 0; mf < 4; ++mf)
#pragma unroll
            for (int r = 0; r < 4; ++r) {
                float p = __expf(acc[mf][nf][r] - m);
                acc[mf][nf][r] = p;
                s += p;
            }
        s += __shfl_xor(s, 16);
        s += __shfl_xor(s, 32);
        const float inv = 1.0f / s;
        const int n = nblk * 128 + w * 32 + nf * 16 + c;
#pragma unroll
        for (int mf = 0; mf < 4; ++mf) {
#pragma unroll
            for (int r = 0; r < 4; ++r) {
                float p = acc[mf][nf][r] * inv;
                ps[mf][r] += p;
                const int k = mf * 16 + g * 4 + r;
                P[((size_t)b * KCL + k) * NPOS + n] = packf(p);
            }
        }
    }
#pragma unroll
    for (int mf = 0; mf < 4; ++mf)
#pragma unroll
        for (int r = 0; r < 4; ++r) {
            float v = ps[mf][r];
            v += __shfl_xor(v, 1);
            v += __shfl_xor(v, 2);
            v += __shfl_xor(v, 4);
            v += __shfl_xor(v, 8);
            ps[mf][r] = v;
        }
    if (c == 0) {
#pragma unroll
        for (int mf = 0; mf < 4; ++mf) {
            float4 o = make_float4(ps[mf][0], ps[mf][1], ps[mf][2], ps[mf][3]);
            *(float4*)&pssum[((size_t)b * 128 + nblk * 4 + w) * KCL + mf * 16 + g * 4] = o;
        }
    }
}

// ---------------------------------------------------------------------------
__global__ void k_mid(const float* __restrict__ pssum, float* __restrict__ ssum) {
    const int b = blockIdx.x, k = threadIdx.x;
    float a = 0.f;
    for (int nw = 0; nw < 128; ++nw) a += pssum[((size_t)b * 128 + nw) * KCL + k];
    ssum[b * KCL + k] = a;
}

// ---------------------------------------------------------------------------
// part[ns][b][k][d] = sum_{n in slice} desc[b][d][n] * P[b][n][k]
// grid (4 dblk, 8 ns, B), 256 thr; tile [128d][64k]. Packed u32 tiles, pitch 66.
// T14 async-STAGE split: nt+1 global loads issued before nt's compute phase.
__global__ __launch_bounds__(256) void k_agg(const float* __restrict__ desc,
        const u32* __restrict__ P, float* __restrict__ part, int B) {
    const int dblk = blockIdx.x, ns = blockIdx.y, b = blockIdx.z;
    const int t = threadIdx.x;
    const int w = t >> 6, lane = t & 63, c = lane & 15, g = lane >> 4;
    const int wm = w & 1, wk = w >> 1;

    __shared__ u32 Apk[128][66];   // desc packed [d][n]
    __shared__ u32 Pt[64][66];     // P packed [k][n]

    f32x4 acc[4][2];
#pragma unroll
    for (int mf = 0; mf < 4; ++mf)
#pragma unroll
        for (int nf = 0; nf < 2; ++nf) acc[mf][nf] = (f32x4){0.f, 0.f, 0.f, 0.f};

    const int rl = t >> 2, q = t & 3;

    // register staging: current + next tile
    float4 dcur[8], dnxt[8];
    uint4  pcur[4], pnxt[4];
    {
        const int n0 = ns * 512;
#pragma unroll
        for (int rr = 0; rr < 2; ++rr) {
            const float* s = desc + ((size_t)b * DDIM + dblk * 128 + rr * 64 + rl) * NPOS + n0;
#pragma unroll
            for (int u = 0; u < 4; ++u) dcur[rr * 4 + u] = *(const float4*)&s[u * 16 + q * 4];
        }
        const u32* pr = P + ((size_t)b * KCL + rl) * NPOS + n0;
#pragma unroll
        for (int u = 0; u < 4; ++u) pcur[u] = *(const uint4*)&pr[u * 16 + q * 4];
    }

    for (int nt = 0; nt < 8; ++nt) {
        // write phase: pack current regs -> LDS
#pragma unroll
        for (int rr = 0; rr < 2; ++rr) {
            const int row = rr * 64 + rl;
#pragma unroll
            for (int u = 0; u < 4; ++u) {
                const int n = u * 16 + q * 4;
                float4 dv = dcur[rr * 4 + u];
                *(uint2*)&Apk[row][n]     = make_uint2(packf(dv.x), packf(dv.y));
                *(uint2*)&Apk[row][n + 2] = make_uint2(packf(dv.z), packf(dv.w));
            }
        }
#pragma unroll
        for (int u = 0; u < 4; ++u) {
            const int n = u * 16 + q * 4;
            uint4 v = pcur[u];
            *(uint2*)&Pt[rl][n]     = make_uint2(v.x, v.y);
            *(uint2*)&Pt[rl][n + 2] = make_uint2(v.z, v.w);
        }
        __syncthreads();
        // prefetch nt+1 (in flight across compute)
        if (nt < 7) {
            const int n0 = ns * 512 + (nt + 1) * 64;
#pragma unroll
            for (int rr = 0; rr < 2; ++rr) {
                const float* s = desc + ((size_t)b * DDIM + dblk * 128 + rr * 64 + rl) * NPOS + n0;
#pragma unroll
                for (int u = 0; u < 4; ++u) dnxt[rr * 4 + u] = *(const float4*)&s[u * 16 + q * 4];
            }
            const u32* pr = P + ((size_t)b * KCL + rl) * NPOS + n0;
#pragma unroll
            for (int u = 0; u < 4; ++u) pnxt[u] = *(const uint4*)&pr[u * 16 + q * 4];
        }
        // compute phase
#pragma unroll
        for (int ks = 0; ks < 2; ++ks) {
            const int kk = ks * 32 + g * 8;
            short8 ah[4], al[4];
#pragma unroll
            for (int mf = 0; mf < 4; ++mf) {
                const u32* ar = &Apk[wm * 64 + mf * 16 + c][kk];
                unpk2(*(const uint2*)&ar[0], *(const uint2*)&ar[2],
                      *(const uint2*)&ar[4], *(const uint2*)&ar[6], ah[mf], al[mf]);
            }
#pragma unroll
            for (int nf = 0; nf < 2; ++nf) {
                const u32* pr2 = &Pt[wk * 32 + nf * 16 + c][kk];
                short8 bh, bl;
                unpk2(*(const uint2*)&pr2[0], *(const uint2*)&pr2[2],
                      *(const uint2*)&pr2[4], *(const uint2*)&pr2[6], bh, bl);
#pragma unroll
                for (int mf = 0; mf < 4; ++mf) {
                    acc[mf][nf] = __builtin_amdgcn_mfma_f32_16x16x32_bf16(ah[mf], bh, acc[mf][nf], 0, 0, 0);
                    acc[mf][nf] = __builtin_amdgcn_mfma_f32_16x16x32_bf16(al[mf], bh, acc[mf][nf], 0, 0, 0);
                    acc[mf][nf] = __builtin_amdgcn_mfma_f32_16x16x32_bf16(ah[mf], bl, acc[mf][nf], 0, 0, 0);
                }
            }
        }
        __syncthreads();
        if (nt < 7) {
#pragma unroll
            for (int u = 0; u < 8; ++u) dcur[u] = dnxt[u];
#pragma unroll
            for (int u = 0; u < 4; ++u) pcur[u] = pnxt[u];
        }
    }
#pragma unroll
    for (int nf = 0; nf < 2; ++nf) {
        const int k = wk * 32 + nf * 16 + c;
#pragma unroll
        for (int mf = 0; mf < 4; ++mf) {
            float4 o = make_float4(acc[mf][nf][0], acc[mf][nf][1], acc[mf][nf][2], acc[mf][nf][3]);
            *(float4*)&part[(((size_t)ns * B + b) * KCL + k) * DDIM + dblk * 128 + wm * 64 + mf * 16 + g * 4] = o;
        }
    }
}

// ---------------------------------------------------------------------------
// finalA: per (b,k): reduce 8 partials, subtract centers*ssum, write centered v
// into agg[b][k][d], and per-column sum-of-squares into cn2[b][k].
__global__ __launch_bounds__(256) void k_finalA(const float* __restrict__ part,
        const float* __restrict__ centers, const float* __restrict__ ssum,
        float* __restrict__ agg, float* __restrict__ cn2, int B) {
    const int bk = blockIdx.x;
    const int b = bk >> 6, k = bk & 63;
    const int t = threadIdx.x;
    const float sm = ssum[bk];
    const int d = t * 2;

    float2 a = make_float2(0.f, 0.f);
#pragma unroll
    for (int ns = 0; ns < NSPL; ++ns) {
        float2 v = *(const float2*)&part[(((size_t)ns * B + b) * KCL + k) * DDIM + d];
        a.x += v.x; a.y += v.y;
    }
    float c0 = centers[(size_t)d * KCL + k];
    float c1 = centers[(size_t)(d + 1) * KCL + k];
    float v0 = fmaf(-c0, sm, a.x);
    float v1 = fmaf(-c1, sm, a.y);
    *(float2*)&agg[((size_t)b * KCL + k) * DDIM + d] = make_float2(v0, v1);

    float sq = fmaf(v0, v0, v1 * v1);
#pragma unroll
    for (int off = 32; off >= 1; off >>= 1) sq += __shfl_xor(sq, off);
    __shared__ float red[4];
    if ((t & 63) == 0) red[t >> 6] = sq;
    __syncthreads();
    if (t == 0) cn2[bk] = red[0] + red[1] + red[2] + red[3];
}

// ---------------------------------------------------------------------------
// finalB: gn per batch from cn2; out[b][d][k] = agg[b][k][d] / (gn*cl_k)
// via LDS transpose. grid (8 dc, B), 256 thr.
__global__ __launch_bounds__(256) void k_finalB(const float* __restrict__ agg,
        const float* __restrict__ cn2, float* __restrict__ out) {
    const int dc = blockIdx.x, b = blockIdx.y;
    const int t = threadIdx.x, r = t >> 2, q = t & 3;
    __shared__ float Lx[64][65];
    __shared__ float invs[64];

    if (t < 64) {
        float c2 = cn2[b * KCL + t];
        float cl = fmaxf(sqrtf(c2), EPSF);
        float tk = c2 / (cl * cl);
        float s = tk;
#pragma unroll
        for (int off = 32; off >= 1; off >>= 1) s += __shfl_xor(s, off);
        float gn = fmaxf(sqrtf(s), EPSF);
        invs[t] = 1.0f / (gn * cl);
    }
    __syncthreads();
    const float ic = invs[r];
#pragma unroll
    for (int u = 0; u < 4; ++u) {
        const int d = q * 16 + u * 4;
        float4 a = *(const float4*)&agg[((size_t)b * KCL + r) * DDIM + dc * 64 + d];
        Lx[r][d]     = a.x * ic;
        Lx[r][d + 1] = a.y * ic;
        Lx[r][d + 2] = a.z * ic;
        Lx[r][d + 3] = a.w * ic;
    }
    __syncthreads();
#pragma unroll
    for (int u = 0; u < 4; ++u) {
        const int k = q * 16 + u * 4;
        float4 o = make_float4(Lx[k][r], Lx[k + 1][r], Lx[k + 2][r], Lx[k + 3][r]);
        *(float4*)&out[((size_t)b * DDIM + dc * 64 + r) * KCL + k] = o;
    }
}

// ---------------------------------------------------------------------------
extern "C" void kernel_launch(void* const* d_in, const int* in_sizes, int n_in,
                              void* d_out, int out_size, void* d_ws, size_t ws_size,
                              hipStream_t stream) {
    const float* desc    = (const float*)d_in[0];
    const float* W       = (const float*)d_in[1];
    const float* bias    = (const float*)d_in[2];
    const float* centers = (const float*)d_in[3];
    float* out = (float*)d_out;

    const int B = in_sizes[0] / (DDIM * NPOS);  // 16

    char* ws = (char*)d_ws;
    const size_t pSz    = (size_t)B * KCL * NPOS * 4;        // 16.78 MB (packed u32)
    const size_t partSz = (size_t)NSPL * B * KCL * DDIM * 4; // 16.78 MB
    u32*   P     = (u32*)ws;
    float* part  = (float*)(ws + pSz);
    float* pssum = part;  // aliased: consumed by k_mid before k_agg writes part
    float* agg   = (float*)(ws + pSz + partSz);
    float* ssum  = agg + (size_t)B * KCL * DDIM;
    float* cn2   = ssum + B * KCL;

    k_scores<<<dim3(NPOS / 128, B), 256, 0, stream>>>(desc, W, bias, P, pssum);
    k_mid<<<B, 64, 0, stream>>>(pssum, ssum);
    k_agg<<<dim3(4, NSPL, B), 256, 0, stream>>>(desc, P, part, B);
    k_finalA<<<B * KCL, 256, 0, stream>>>(part, centers, ssum, agg, cn2, B);
    k_finalB<<<dim3(8, B), 256, 0, stream>>>(agg, cn2, out);
}

// Round 10
// 77.016 us; speedup vs baseline: 1.6231x; 1.0607x over previous
//
#include <hip/hip_runtime.h>
#include <hip/hip_bf16.h>
#include <math.h>

typedef __attribute__((ext_vector_type(8))) short short8;
typedef __attribute__((ext_vector_type(4))) float f32x4;
typedef __attribute__((ext_vector_type(4))) unsigned short u16x4;
typedef unsigned int u32;
typedef unsigned short u16;

#define DDIM 512
#define KCL 64
#define NPOS 4096
#define NSPL 8
#define EPSF 1e-12f

__device__ __forceinline__ u16 f2bf(float x) {
    __hip_bfloat16 h = __float2bfloat16(x);
    return __builtin_bit_cast(u16, h);
}
__device__ __forceinline__ float bf2f(u16 u) {
    unsigned i = ((unsigned)u) << 16;
    return __builtin_bit_cast(float, i);
}
// pack x as bf16(hi) | bf16(residual lo) << 16
__device__ __forceinline__ u32 packf(float x) {
    u16 h = f2bf(x);
    u16 l = f2bf(x - bf2f(h));
    return (u32)h | ((u32)l << 16);
}
// 8 packed u32 (as 4 uint2) -> hi/lo bf16 short8
__device__ __forceinline__ void unpk2(uint2 a0, uint2 a1, uint2 a2, uint2 a3,
                                      short8& hi, short8& lo) {
    uint4 H, L;
    H.x = (a0.x & 0xffffu) | (a0.y << 16);
    L.x = (a0.x >> 16)     | (a0.y & 0xffff0000u);
    H.y = (a1.x & 0xffffu) | (a1.y << 16);
    L.y = (a1.x >> 16)     | (a1.y & 0xffff0000u);
    H.z = (a2.x & 0xffffu) | (a2.y << 16);
    L.z = (a2.x >> 16)     | (a2.y & 0xffff0000u);
    H.w = (a3.x & 0xffffu) | (a3.y << 16);
    L.w = (a3.x >> 16)     | (a3.y & 0xffff0000u);
    hi = __builtin_bit_cast(short8, H);
    lo = __builtin_bit_cast(short8, L);
}

// ---------------------------------------------------------------------------
// scores = softmax_k(W @ desc + b) -> P packed u32 [B][K][N], pssum partials.
// grid (32 nblk, B), 256 thr = 4 waves x (64k x 32n). Split-bf16 hh+lh+hl.
// T14 reg-dbuf + transpose-at-write: desc staged as DT[n][d] packed u32
// (scalar b32 writes, <=2-way banks; uint2 frag reads at b64 floor).
__global__ __launch_bounds__(256) void k_scores(const float* __restrict__ desc,
        const float* __restrict__ W, const float* __restrict__ bias,
        u32* __restrict__ P, float* __restrict__ pssum) {
    const int nblk = blockIdx.x, b = blockIdx.y;
    const int t = threadIdx.x;
    const int w = t >> 6, lane = t & 63, c = lane & 15, g = lane >> 4;

    __shared__ u16 Wh[64][72], Wl[64][72];   // [k][d] pitch 72 (b128 reads at floor)
    __shared__ u32 DT[128][66];              // [n][d] packed, pitch 66

    f32x4 acc[4][2];
#pragma unroll
    for (int mf = 0; mf < 4; ++mf)
#pragma unroll
        for (int nf = 0; nf < 2; ++nf) acc[mf][nf] = (f32x4){0.f, 0.f, 0.f, 0.f};

    const int rl = t >> 2, q = t & 3;

    // register staging buffers (current + next)
    float4 dcur[8], wcur[4], dnxt[8], wnxt[4];
    {
        const float* dsrc = desc + ((size_t)b * DDIM + rl) * NPOS + nblk * 128;
        const float* wsrc = W + (size_t)rl * DDIM;
#pragma unroll
        for (int u = 0; u < 8; ++u) dcur[u] = *(const float4*)&dsrc[u * 16 + q * 4];
#pragma unroll
        for (int u = 0; u < 4; ++u) wcur[u] = *(const float4*)&wsrc[u * 16 + q * 4];
    }

#pragma unroll
    for (int dt = 0; dt < 8; ++dt) {
        // write phase: W split planes; desc transposed+packed
#pragma unroll
        for (int u = 0; u < 4; ++u) {
            const int dd = u * 16 + q * 4;
            float4 wv = wcur[u];
            u16 h0 = f2bf(wv.x), h1 = f2bf(wv.y), h2 = f2bf(wv.z), h3 = f2bf(wv.w);
            *(u16x4*)&Wh[rl][dd] = (u16x4){h0, h1, h2, h3};
            *(u16x4*)&Wl[rl][dd] = (u16x4){f2bf(wv.x - bf2f(h0)), f2bf(wv.y - bf2f(h1)),
                                           f2bf(wv.z - bf2f(h2)), f2bf(wv.w - bf2f(h3))};
        }
#pragma unroll
        for (int u = 0; u < 8; ++u) {
            const int n = u * 16 + q * 4;
            float4 dv = dcur[u];
            DT[n + 0][rl] = packf(dv.x);
            DT[n + 1][rl] = packf(dv.y);
            DT[n + 2][rl] = packf(dv.z);
            DT[n + 3][rl] = packf(dv.w);
        }
        __syncthreads();
        // prefetch dt+1 (in flight across the compute phase)
        if (dt < 7) {
            const int d0 = (dt + 1) * 64;
            const float* dsrc = desc + ((size_t)b * DDIM + d0 + rl) * NPOS + nblk * 128;
            const float* wsrc = W + (size_t)rl * DDIM + d0;
#pragma unroll
            for (int u = 0; u < 8; ++u) dnxt[u] = *(const float4*)&dsrc[u * 16 + q * 4];
#pragma unroll
            for (int u = 0; u < 4; ++u) wnxt[u] = *(const float4*)&wsrc[u * 16 + q * 4];
        }
        // compute phase
#pragma unroll
        for (int ks = 0; ks < 2; ++ks) {
            const int kk = ks * 32 + g * 8;
            short8 ah[4], al[4];
#pragma unroll
            for (int mf = 0; mf < 4; ++mf) {
                ah[mf] = *(const short8*)&Wh[mf * 16 + c][kk];
                al[mf] = *(const short8*)&Wl[mf * 16 + c][kk];
            }
#pragma unroll
            for (int nf = 0; nf < 2; ++nf) {
                const int nc = w * 32 + nf * 16 + c;
                const u32* dr = &DT[nc][kk];
                short8 bh, bl;
                unpk2(*(const uint2*)&dr[0], *(const uint2*)&dr[2],
                      *(const uint2*)&dr[4], *(const uint2*)&dr[6], bh, bl);
#pragma unroll
                for (int mf = 0; mf < 4; ++mf) {
                    acc[mf][nf] = __builtin_amdgcn_mfma_f32_16x16x32_bf16(ah[mf], bh, acc[mf][nf], 0, 0, 0);
                    acc[mf][nf] = __builtin_amdgcn_mfma_f32_16x16x32_bf16(al[mf], bh, acc[mf][nf], 0, 0, 0);
                    acc[mf][nf] = __builtin_amdgcn_mfma_f32_16x16x32_bf16(ah[mf], bl, acc[mf][nf], 0, 0, 0);
                }
            }
        }
        __syncthreads();
        if (dt < 7) {
#pragma unroll
            for (int u = 0; u < 8; ++u) dcur[u] = dnxt[u];
#pragma unroll
            for (int u = 0; u < 4; ++u) wcur[u] = wnxt[u];
        }
    }

    // epilogue: +bias, softmax over 64 k, pack+store P, ssum partials
#pragma unroll
    for (int mf = 0; mf < 4; ++mf) {
        f32x4 bv = *(const f32x4*)&bias[mf * 16 + g * 4];
#pragma unroll
        for (int nf = 0; nf < 2; ++nf) acc[mf][nf] = acc[mf][nf] + bv;
    }

    float ps[4][4];
#pragma unroll
    for (int mf = 0; mf < 4; ++mf)
#pragma unroll
        for (int r = 0; r < 4; ++r) ps[mf][r] = 0.f;

#pragma unroll
    for (int nf = 0; nf < 2; ++nf) {
        float m = acc[0][nf][0];
#pragma unroll
        for (int mf = 0; mf < 4; ++mf)
#pragma unroll
            for (int r = 0; r < 4; ++r) m = fmaxf(m, acc[mf][nf][r]);
        m = fmaxf(m, __shfl_xor(m, 16));
        m = fmaxf(m, __shfl_xor(m, 32));
        float s = 0.f;
#pragma unroll
        for (int mf = 0; mf < 4; ++mf)
#pragma unroll
            for (int r = 0; r < 4; ++r) {
                float p = __expf(acc[mf][nf][r] - m);
                acc[mf][nf][r] = p;
                s += p;
            }
        s += __shfl_xor(s, 16);
        s += __shfl_xor(s, 32);
        const float inv = 1.0f / s;
        const int n = nblk * 128 + w * 32 + nf * 16 + c;
#pragma unroll
        for (int mf = 0; mf < 4; ++mf) {
#pragma unroll
            for (int r = 0; r < 4; ++r) {
                float p = acc[mf][nf][r] * inv;
                ps[mf][r] += p;
                const int k = mf * 16 + g * 4 + r;
                P[((size_t)b * KCL + k) * NPOS + n] = packf(p);
            }
        }
    }
#pragma unroll
    for (int mf = 0; mf < 4; ++mf)
#pragma unroll
        for (int r = 0; r < 4; ++r) {
            float v = ps[mf][r];
            v += __shfl_xor(v, 1);
            v += __shfl_xor(v, 2);
            v += __shfl_xor(v, 4);
            v += __shfl_xor(v, 8);
            ps[mf][r] = v;
        }
    if (c == 0) {
#pragma unroll
        for (int mf = 0; mf < 4; ++mf) {
            float4 o = make_float4(ps[mf][0], ps[mf][1], ps[mf][2], ps[mf][3]);
            *(float4*)&pssum[((size_t)b * 128 + nblk * 4 + w) * KCL + mf * 16 + g * 4] = o;
        }
    }
}

// ---------------------------------------------------------------------------
// part[ns][b][k][d] = sum_{n in slice} desc[b][d][n] * P[b][n][k]
// grid (4 dblk, 8 ns, B), 256 thr; tile [128d][64k]. Packed u32 tiles, pitch 66.
// T14 async-STAGE split: nt+1 global loads issued before nt's compute phase.
__global__ __launch_bounds__(256) void k_agg(const float* __restrict__ desc,
        const u32* __restrict__ P, float* __restrict__ part, int B) {
    const int dblk = blockIdx.x, ns = blockIdx.y, b = blockIdx.z;
    const int t = threadIdx.x;
    const int w = t >> 6, lane = t & 63, c = lane & 15, g = lane >> 4;
    const int wm = w & 1, wk = w >> 1;

    __shared__ u32 Apk[128][66];   // desc packed [d][n]
    __shared__ u32 Pt[64][66];     // P packed [k][n]

    f32x4 acc[4][2];
#pragma unroll
    for (int mf = 0; mf < 4; ++mf)
#pragma unroll
        for (int nf = 0; nf < 2; ++nf) acc[mf][nf] = (f32x4){0.f, 0.f, 0.f, 0.f};

    const int rl = t >> 2, q = t & 3;

    // register staging: current + next tile
    float4 dcur[8], dnxt[8];
    uint4  pcur[4], pnxt[4];
    {
        const int n0 = ns * 512;
#pragma unroll
        for (int rr = 0; rr < 2; ++rr) {
            const float* s = desc + ((size_t)b * DDIM + dblk * 128 + rr * 64 + rl) * NPOS + n0;
#pragma unroll
            for (int u = 0; u < 4; ++u) dcur[rr * 4 + u] = *(const float4*)&s[u * 16 + q * 4];
        }
        const u32* pr = P + ((size_t)b * KCL + rl) * NPOS + n0;
#pragma unroll
        for (int u = 0; u < 4; ++u) pcur[u] = *(const uint4*)&pr[u * 16 + q * 4];
    }

    for (int nt = 0; nt < 8; ++nt) {
        // write phase: pack current regs -> LDS
#pragma unroll
        for (int rr = 0; rr < 2; ++rr) {
            const int row = rr * 64 + rl;
#pragma unroll
            for (int u = 0; u < 4; ++u) {
                const int n = u * 16 + q * 4;
                float4 dv = dcur[rr * 4 + u];
                *(uint2*)&Apk[row][n]     = make_uint2(packf(dv.x), packf(dv.y));
                *(uint2*)&Apk[row][n + 2] = make_uint2(packf(dv.z), packf(dv.w));
            }
        }
#pragma unroll
        for (int u = 0; u < 4; ++u) {
            const int n = u * 16 + q * 4;
            uint4 v = pcur[u];
            *(uint2*)&Pt[rl][n]     = make_uint2(v.x, v.y);
            *(uint2*)&Pt[rl][n + 2] = make_uint2(v.z, v.w);
        }
        __syncthreads();
        // prefetch nt+1 (in flight across compute)
        if (nt < 7) {
            const int n0 = ns * 512 + (nt + 1) * 64;
#pragma unroll
            for (int rr = 0; rr < 2; ++rr) {
                const float* s = desc + ((size_t)b * DDIM + dblk * 128 + rr * 64 + rl) * NPOS + n0;
#pragma unroll
                for (int u = 0; u < 4; ++u) dnxt[rr * 4 + u] = *(const float4*)&s[u * 16 + q * 4];
            }
            const u32* pr = P + ((size_t)b * KCL + rl) * NPOS + n0;
#pragma unroll
            for (int u = 0; u < 4; ++u) pnxt[u] = *(const uint4*)&pr[u * 16 + q * 4];
        }
        // compute phase
#pragma unroll
        for (int ks = 0; ks < 2; ++ks) {
            const int kk = ks * 32 + g * 8;
            short8 ah[4], al[4];
#pragma unroll
            for (int mf = 0; mf < 4; ++mf) {
                const u32* ar = &Apk[wm * 64 + mf * 16 + c][kk];
                unpk2(*(const uint2*)&ar[0], *(const uint2*)&ar[2],
                      *(const uint2*)&ar[4], *(const uint2*)&ar[6], ah[mf], al[mf]);
            }
#pragma unroll
            for (int nf = 0; nf < 2; ++nf) {
                const u32* pr2 = &Pt[wk * 32 + nf * 16 + c][kk];
                short8 bh, bl;
                unpk2(*(const uint2*)&pr2[0], *(const uint2*)&pr2[2],
                      *(const uint2*)&pr2[4], *(const uint2*)&pr2[6], bh, bl);
#pragma unroll
                for (int mf = 0; mf < 4; ++mf) {
                    acc[mf][nf] = __builtin_amdgcn_mfma_f32_16x16x32_bf16(ah[mf], bh, acc[mf][nf], 0, 0, 0);
                    acc[mf][nf] = __builtin_amdgcn_mfma_f32_16x16x32_bf16(al[mf], bh, acc[mf][nf], 0, 0, 0);
                    acc[mf][nf] = __builtin_amdgcn_mfma_f32_16x16x32_bf16(ah[mf], bl, acc[mf][nf], 0, 0, 0);
                }
            }
        }
        __syncthreads();
        if (nt < 7) {
#pragma unroll
            for (int u = 0; u < 8; ++u) dcur[u] = dnxt[u];
#pragma unroll
            for (int u = 0; u < 4; ++u) pcur[u] = pnxt[u];
        }
    }
#pragma unroll
    for (int nf = 0; nf < 2; ++nf) {
        const int k = wk * 32 + nf * 16 + c;
#pragma unroll
        for (int mf = 0; mf < 4; ++mf) {
            float4 o = make_float4(acc[mf][nf][0], acc[mf][nf][1], acc[mf][nf][2], acc[mf][nf][3]);
            *(float4*)&part[(((size_t)ns * B + b) * KCL + k) * DDIM + dblk * 128 + wm * 64 + mf * 16 + g * 4] = o;
        }
    }
}

// ---------------------------------------------------------------------------
// finalA: per (b,k): ssum from pssum partials (fused k_mid), reduce 8 agg
// partials, subtract centers*ssum, write centered v into agg[b][k][d] and
// column sum-of-squares into cn2[b][k]. grid B*K, 256 thr.
__global__ __launch_bounds__(256) void k_finalA(const float* __restrict__ part,
        const float* __restrict__ pssum, const float* __restrict__ centers,
        float* __restrict__ agg, float* __restrict__ cn2, int B) {
    const int bk = blockIdx.x;
    const int b = bk >> 6, k = bk & 63;
    const int t = threadIdx.x;
    __shared__ float red[4];
    __shared__ float smsh;

    // ssum: sum 128 pssum partials for this (b,k)
    float v = (t < 128) ? pssum[((size_t)b * 128 + t) * KCL + k] : 0.f;
#pragma unroll
    for (int off = 32; off >= 1; off >>= 1) v += __shfl_xor(v, off);
    if ((t & 63) == 0) red[t >> 6] = v;
    __syncthreads();
    if (t == 0) smsh = red[0] + red[1];
    __syncthreads();
    const float sm = smsh;

    const int d = t * 2;
    float2 a = make_float2(0.f, 0.f);
#pragma unroll
    for (int ns = 0; ns < NSPL; ++ns) {
        float2 pv = *(const float2*)&part[(((size_t)ns * B + b) * KCL + k) * DDIM + d];
        a.x += pv.x; a.y += pv.y;
    }
    float c0 = centers[(size_t)d * KCL + k];
    float c1 = centers[(size_t)(d + 1) * KCL + k];
    float v0 = fmaf(-c0, sm, a.x);
    float v1 = fmaf(-c1, sm, a.y);
    *(float2*)&agg[((size_t)b * KCL + k) * DDIM + d] = make_float2(v0, v1);

    float sq = fmaf(v0, v0, v1 * v1);
#pragma unroll
    for (int off = 32; off >= 1; off >>= 1) sq += __shfl_xor(sq, off);
    __syncthreads();
    if ((t & 63) == 0) red[t >> 6] = sq;
    __syncthreads();
    if (t == 0) cn2[bk] = red[0] + red[1] + red[2] + red[3];
}

// ---------------------------------------------------------------------------
// finalB: gn per batch from cn2; out[b][d][k] = agg[b][k][d] / (gn*cl_k)
// via LDS transpose. grid (8 dc, B), 256 thr.
__global__ __launch_bounds__(256) void k_finalB(const float* __restrict__ agg,
        const float* __restrict__ cn2, float* __restrict__ out) {
    const int dc = blockIdx.x, b = blockIdx.y;
    const int t = threadIdx.x, r = t >> 2, q = t & 3;
    __shared__ float Lx[64][65];
    __shared__ float invs[64];

    if (t < 64) {
        float c2 = cn2[b * KCL + t];
        float cl = fmaxf(sqrtf(c2), EPSF);
        float tk = c2 / (cl * cl);
        float s = tk;
#pragma unroll
        for (int off = 32; off >= 1; off >>= 1) s += __shfl_xor(s, off);
        float gn = fmaxf(sqrtf(s), EPSF);
        invs[t] = 1.0f / (gn * cl);
    }
    __syncthreads();
    const float ic = invs[r];
#pragma unroll
    for (int u = 0; u < 4; ++u) {
        const int d = q * 16 + u * 4;
        float4 a = *(const float4*)&agg[((size_t)b * KCL + r) * DDIM + dc * 64 + d];
        Lx[r][d]     = a.x * ic;
        Lx[r][d + 1] = a.y * ic;
        Lx[r][d + 2] = a.z * ic;
        Lx[r][d + 3] = a.w * ic;
    }
    __syncthreads();
#pragma unroll
    for (int u = 0; u < 4; ++u) {
        const int k = q * 16 + u * 4;
        float4 o = make_float4(Lx[k][r], Lx[k + 1][r], Lx[k + 2][r], Lx[k + 3][r]);
        *(float4*)&out[((size_t)b * DDIM + dc * 64 + r) * KCL + k] = o;
    }
}

// ---------------------------------------------------------------------------
extern "C" void kernel_launch(void* const* d_in, const int* in_sizes, int n_in,
                              void* d_out, int out_size, void* d_ws, size_t ws_size,
                              hipStream_t stream) {
    const float* desc    = (const float*)d_in[0];
    const float* W       = (const float*)d_in[1];
    const float* bias    = (const float*)d_in[2];
    const float* centers = (const float*)d_in[3];
    float* out = (float*)d_out;

    const int B = in_sizes[0] / (DDIM * NPOS);  // 16

    char* ws = (char*)d_ws;
    const size_t pSz    = (size_t)B * KCL * NPOS * 4;        // 16.78 MB (packed u32)
    const size_t partSz = (size_t)NSPL * B * KCL * DDIM * 4; // 16.78 MB
    u32*   P     = (u32*)ws;
    float* part  = (float*)(ws + pSz);
    float* agg   = (float*)(ws + pSz + partSz);
    float* cn2   = agg + (size_t)B * KCL * DDIM;
    float* pssum = cn2 + B * KCL;                            // 512 KB, own buffer

    k_scores<<<dim3(NPOS / 128, B), 256, 0, stream>>>(desc, W, bias, P, pssum);
    k_agg<<<dim3(4, NSPL, B), 256, 0, stream>>>(desc, P, part, B);
    k_finalA<<<B * KCL, 256, 0, stream>>>(part, pssum, centers, agg, cn2, B);
    k_finalB<<<dim3(8, B), 256, 0, stream>>>(agg, cn2, out);
}